// Round 5
// baseline (306.825 us; speedup 1.0000x reference)
//
#include <hip/hip_runtime.h>
#include <hip/hip_bf16.h>
#include <math.h>

// ---------------------------------------------------------------------------
// FaceAttnProcessor forward. R14:
// - ff2 reverted to gemm64 split-K z=2 (R13's gemm_bf16 z=4 = 384 blocks =
//   1.5 occupancy rounds, ~25% round-2 utilization tax; 768 blocks = 3 full
//   rounds is the right shape).
// - wo GEMM z=2 -> z=1 with gemm64's fused bias+res+alpha epilogue writing
//   fp32 x1 directly (no partial slabs); woepi_ln nz==0 mode reads x1 and
//   does only the double-LN. Saves ~50 MB slab round-trip.
// - self-attn stays nchunk=1 (in-kernel normalize, no merge).
// 12 launches. B=2, N=1024, C=768, H=12, INNER=3072.
// ---------------------------------------------------------------------------

#define C_DIM 768
#define B_DIM 2
#define N_DIM 1024
#define NC_DIM 1040
#define L_DIM 93
#define TEXT_LEN 77
#define INNER 3072
#define MNX 1572864   // 2048*768

typedef unsigned short ushort_t;
typedef __bf16 bf16x8 __attribute__((ext_vector_type(8)));
typedef float f32x4 __attribute__((ext_vector_type(4)));

__device__ __forceinline__ ushort_t f2b(float f) {
  __hip_bfloat16 h = __float2bfloat16(f);
  return *(ushort_t*)&h;
}
__device__ __forceinline__ float b2f(ushort_t u) {
  __hip_bfloat16 h = *(__hip_bfloat16*)&u;
  return __bfloat162float(h);
}

__device__ __forceinline__ void g2lds16(const void* g, void* l) {
  __builtin_amdgcn_global_load_lds(
      (const __attribute__((address_space(1))) unsigned int*)g,
      (__attribute__((address_space(3))) unsigned int*)l, 16, 0, 0);
}

// ---------------- workspace map (byte offsets) ----------------------------
#define WX1    0u           // fp32 x1 (2048*768)
#define WX2    6291456u     // fp32 x2
#define WQKV   12582912u    // u16 qkv_b [2080][2304]; later q2b/kv2b
#define WBB1   22167552u    // comb_b / split-K partial slabs (<=4)
#define WG     47333376u    // attn_b (phase A) / g_b (phase C)
#define WS1    59916288u    // u16 hh / x2b [2048][768]
#define WTEXT  63062016u    // u16 text_b [154][768]
#define WATT2  63298560u    // u16 attn2b [2048][768]
#define WWQKV  66444288u    // u16 wqkv_t [2304][768]
#define WWO    69983232u    // u16 wo_t   [768][768]
#define WW1    71162880u    // u16 w1_t   [6144][768] (interleaved a/gate rows)
#define WW2    80600064u    // u16 w2_t   [768][3072]
#define WCAWQ  85318656u    // u16 cawq_t [768][768]
#define WCAKV  86498304u    // u16 cakv_t [1536][768]
#define WCAWO  88857600u    // u16 cawo_t [768][768]
#define WVT1   90037248u    // u16 Vt self  [2][12][64][1088]
#define WVT2   93379584u    // u16 Vt cross [2][12][64][128]
#define WATTN  (WG + 524288u)       // u16 attn_b (dead before g_b written)
#define WPART  WBB1                 // fp32 split-K partials (<=4 slabs = 25.2MB)
// end: 93,772,800 B

// ---------------- block reduction (256 threads = 4 waves) -----------------
__device__ __forceinline__ float block_sum(float v, float* sh) {
#pragma unroll
  for (int o = 32; o > 0; o >>= 1) v += __shfl_down(v, o);
  int lane = threadIdx.x & 63, w = threadIdx.x >> 6;
  if (lane == 0) sh[w] = v;
  __syncthreads();
  float r = sh[0] + sh[1] + sh[2] + sh[3];
  __syncthreads();
  return r;
}

// ---------------- prep: weight transposes + LN/concat + text gather -------
struct WtDesc {
  const float* src[10];
  ushort_t*    dst[10];
  int K[10];
  int N[10];
  int tilesX[10];
  int ileave[10];
  int start[11];
};

__global__ __launch_bounds__(256)
void prep_kernel(WtDesc d,
                 const float* __restrict__ x, const float* __restrict__ enc,
                 const float* __restrict__ g, const float* __restrict__ b,
                 ushort_t* __restrict__ comb, ushort_t* __restrict__ text) {
  __shared__ float tile[64][65];
  int bid = blockIdx.x;
  int nwt = d.start[10];
  if (bid >= nwt) {
    // ---- LN(x)/LN(face) -> comb, or text gather ----
    int r = bid - nwt;
    if (r >= B_DIM * NC_DIM) {
      int i = r - B_DIM * NC_DIM;
      int bb = i / TEXT_LEN, j = i % TEXT_LEN;
      const float* src = enc + ((size_t)bb * L_DIM + j) * C_DIM;
      ushort_t* dst = text + (size_t)i * C_DIM;
#pragma unroll
      for (int l = 0; l < 3; ++l) {
        int c = threadIdx.x + l * 256;
        dst[c] = f2b(src[c]);
      }
      return;
    }
    float* sh = &tile[0][0];
    int bb = r / NC_DIM, i = r % NC_DIM;
    const float* src = (i < N_DIM)
        ? (x   + ((size_t)bb * N_DIM + i) * C_DIM)
        : (enc + ((size_t)bb * L_DIM + TEXT_LEN + (i - N_DIM)) * C_DIM);
    float v[3];
#pragma unroll
    for (int j = 0; j < 3; ++j) v[j] = src[threadIdx.x + j * 256];
    float mean = block_sum(v[0] + v[1] + v[2], sh) * (1.f / C_DIM);
    float sq = 0.f;
#pragma unroll
    for (int j = 0; j < 3; ++j) { float dd = v[j] - mean; sq += dd * dd; }
    float rstd = rsqrtf(block_sum(sq, sh) * (1.f / C_DIM) + 1e-5f);
    ushort_t* dst = comb + (size_t)r * C_DIM;
#pragma unroll
    for (int j = 0; j < 3; ++j) {
      int c = threadIdx.x + j * 256;
      dst[c] = f2b((v[j] - mean) * rstd * g[c] + b[c]);
    }
    return;
  }
  // ---- weight cast+transpose ----
  int j = 0;
  while (j < 9 && bid >= d.start[j + 1]) ++j;
  int ti = bid - d.start[j];
  int K = d.K[j], N = d.N[j];
  int n0 = (ti % d.tilesX[j]) * 64, k0 = (ti / d.tilesX[j]) * 64;
  const float* in = d.src[j];
  ushort_t* out = d.dst[j];
  int il = d.ileave[j];
  int t = threadIdx.x;
#pragma unroll
  for (int p = 0; p < 16; ++p) {
    int idx = t + p * 256;
    int r = idx >> 6, c = idx & 63;
    tile[r][c] = in[(size_t)(k0 + r) * N + n0 + c];
  }
  __syncthreads();
#pragma unroll
  for (int p = 0; p < 16; ++p) {
    int idx = t + p * 256;
    int r = idx >> 6, c = idx & 63;
    int nrow = n0 + r;
    int dstrow = il ? ((nrow < INNER) ? (nrow * 2) : ((nrow - INNER) * 2 + 1)) : nrow;
    out[(size_t)dstrow * K + k0 + c] = f2b(tile[c][r]);
  }
}

// ---------------- bf16 MFMA GEMM, 128x128 tile -----------------------------
// Paths: Og!=null -> fused GEGLU (interleaved a/gate cols); else bf16 Ob.
__global__ __launch_bounds__(256)
void gemm_bf16(const ushort_t* __restrict__ A, const ushort_t* __restrict__ Bt,
               ushort_t* __restrict__ Ob, ushort_t* __restrict__ Og,
               int M, int N, int K) {
  __shared__ ushort_t sA[2][128 * 32];
  __shared__ ushort_t sB[2][128 * 32];
  int t = threadIdx.x;
  int w = t >> 6, ln = t & 63;
  int m0 = blockIdx.y * 128, n0 = blockIdx.x * 128;
  int wm = (w >> 1) * 64, wn = (w & 1) * 64;
  int lr = ln & 15, lq = ln >> 4;
  int seg_r = ln >> 2, seg_c = (ln & 3) * 8;

  f32x4 acc[4][4];
#pragma unroll
  for (int mi = 0; mi < 4; ++mi)
#pragma unroll
    for (int ni = 0; ni < 4; ++ni) acc[mi][ni] = (f32x4){0.f, 0.f, 0.f, 0.f};

#define STAGE(k0_, buf_)                                                     \
  do {                                                                       \
    _Pragma("unroll") for (int l = 0; l < 2; ++l) {                          \
      int s = w * 2 + l;                                                     \
      int arow = m0 + s * 16 + seg_r;                                        \
      arow = arow < M ? arow : M - 1;                                        \
      g2lds16(A + (size_t)arow * K + (k0_) + seg_c, &sA[buf_][s * 512]);     \
      int nrow = n0 + s * 16 + seg_r;                                        \
      g2lds16(Bt + (size_t)nrow * K + (k0_) + seg_c, &sB[buf_][s * 512]);    \
    }                                                                        \
  } while (0)

  STAGE(0, 0);
  __syncthreads();
  int cur = 0;
  for (int k0 = 0; k0 < K; k0 += 32) {
    if (k0 + 32 < K) STAGE(k0 + 32, cur ^ 1);
    bf16x8 af[4], bfr[4];
#pragma unroll
    for (int mi = 0; mi < 4; ++mi)
      af[mi] = *(const bf16x8*)&sA[cur][(wm + mi * 16 + lr) * 32 + lq * 8];
#pragma unroll
    for (int ni = 0; ni < 4; ++ni)
      bfr[ni] = *(const bf16x8*)&sB[cur][(wn + ni * 16 + lr) * 32 + lq * 8];
#pragma unroll
    for (int mi = 0; mi < 4; ++mi)
#pragma unroll
      for (int ni = 0; ni < 4; ++ni)
        acc[mi][ni] = __builtin_amdgcn_mfma_f32_16x16x32_bf16(
            af[mi], bfr[ni], acc[mi][ni], 0, 0, 0);
    __syncthreads();
    cur ^= 1;
  }
#undef STAGE

  if (Og) {
#pragma unroll
    for (int mi = 0; mi < 4; ++mi)
#pragma unroll
      for (int ni = 0; ni < 4; ++ni) {
        int col = n0 + wn + ni * 16 + lr;
#pragma unroll
        for (int r = 0; r < 4; ++r) {
          float val = acc[mi][ni][r];
          float other = __shfl_xor(val, 1);
          if (!(lr & 1)) {
            float a = val, gate = other;
            float ge = 0.5f * gate * (1.f + erff(gate * 0.70710678118654752f));
            int row = m0 + wm + mi * 16 + lq * 4 + r;
            Og[(size_t)row * INNER + (col >> 1)] = f2b(a * ge);
          }
        }
      }
  } else {
#pragma unroll
    for (int mi = 0; mi < 4; ++mi)
#pragma unroll
      for (int ni = 0; ni < 4; ++ni) {
        int col = n0 + wn + ni * 16 + lr;
#pragma unroll
        for (int r = 0; r < 4; ++r) {
          int row = m0 + wm + mi * 16 + lq * 4 + r;
          if (row < M) Ob[(size_t)row * N + col] = f2b(acc[mi][ni][r]);
        }
      }
  }
}

// ---------------- bf16 MFMA GEMM, 64x64 tile, BK=64, optional split-K ------
// 4 waves, each 32x32 subtile (2x2 MFMA). grid.z = K/Ksplit splits;
// Part!=null: fp32 partial slabs; else fused bias/res/alpha epilogue.
// Optional second problem: blocks with blockIdx.y >= ybreak compute
// {A2,Bt2}->Ob2 (bf16 out).
__global__ __launch_bounds__(256)
void gemm64(const ushort_t* __restrict__ A, const ushort_t* __restrict__ Bt,
            float* __restrict__ Out, ushort_t* __restrict__ Ob,
            float* __restrict__ Part,
            int M, int N, int K, int Ksplit,
            const float* __restrict__ bias, const float* __restrict__ res,
            const float* __restrict__ alphaPtr,
            const ushort_t* __restrict__ A2, const ushort_t* __restrict__ Bt2,
            ushort_t* __restrict__ Ob2, int M2, int N2, int ybreak) {
  __shared__ ushort_t sA[2][4096];   // [buf][s*2048 + row*32 + k]
  __shared__ ushort_t sB[2][4096];
  int by = blockIdx.y;
  if (A2 && by >= ybreak) {
    if ((int)blockIdx.x * 64 >= N2) return;
    A = A2; Bt = Bt2; Ob = Ob2; M = M2; N = N2;
    Out = nullptr; Part = nullptr; bias = nullptr; res = nullptr; alphaPtr = nullptr;
    by -= ybreak;
  }
  int t = threadIdx.x;
  int w = t >> 6, ln = t & 63;
  int m0 = by * 64, n0 = blockIdx.x * 64;
  int wm = (w >> 1) * 32, wn = (w & 1) * 32;
  int lr = ln & 15, lq = ln >> 4;
  int srow = (w & 1) * 32 + (ln >> 2);        // staging row (+ i*16)
  int skoff = (w >> 1) * 32 + (ln & 3) * 8;   // staging k offset
  int kbeg = blockIdx.z * Ksplit;
  int kend = kbeg + Ksplit; if (kend > K) kend = K;

  f32x4 acc[2][2];
#pragma unroll
  for (int mi = 0; mi < 2; ++mi)
#pragma unroll
    for (int ni = 0; ni < 2; ++ni) acc[mi][ni] = (f32x4){0.f, 0.f, 0.f, 0.f};

#define STG64(k0_, buf_)                                                      \
  do {                                                                        \
    _Pragma("unroll") for (int i = 0; i < 2; ++i) {                           \
      int ar = m0 + srow + i * 16; ar = ar < M ? ar : M - 1;                  \
      g2lds16(A + (size_t)ar * K + (k0_) + skoff,                             \
              (char*)sA + (buf_) * 8192 + w * 2048 + i * 1024);               \
      int nr = n0 + srow + i * 16;                                            \
      g2lds16(Bt + (size_t)nr * K + (k0_) + skoff,                            \
              (char*)sB + (buf_) * 8192 + w * 2048 + i * 1024);               \
    }                                                                         \
  } while (0)

  STG64(kbeg, 0);
  __syncthreads();
  int cur = 0;
  for (int k0 = kbeg; k0 < kend; k0 += 64) {
    if (k0 + 64 < kend) STG64(k0 + 64, cur ^ 1);
#pragma unroll
    for (int s = 0; s < 2; ++s) {
      bf16x8 a0 = *(const bf16x8*)&sA[cur][s * 2048 + (wm + lr) * 32 + lq * 8];
      bf16x8 a1 = *(const bf16x8*)&sA[cur][s * 2048 + (wm + 16 + lr) * 32 + lq * 8];
      bf16x8 b0 = *(const bf16x8*)&sB[cur][s * 2048 + (wn + lr) * 32 + lq * 8];
      bf16x8 b1 = *(const bf16x8*)&sB[cur][s * 2048 + (wn + 16 + lr) * 32 + lq * 8];
      acc[0][0] = __builtin_amdgcn_mfma_f32_16x16x32_bf16(a0, b0, acc[0][0], 0, 0, 0);
      acc[0][1] = __builtin_amdgcn_mfma_f32_16x16x32_bf16(a0, b1, acc[0][1], 0, 0, 0);
      acc[1][0] = __builtin_amdgcn_mfma_f32_16x16x32_bf16(a1, b0, acc[1][0], 0, 0, 0);
      acc[1][1] = __builtin_amdgcn_mfma_f32_16x16x32_bf16(a1, b1, acc[1][1], 0, 0, 0);
    }
    __syncthreads();
    cur ^= 1;
  }
#undef STG64

  if (Part) {
    float* P = Part + (size_t)blockIdx.z * M * N;
#pragma unroll
    for (int mi = 0; mi < 2; ++mi)
#pragma unroll
      for (int ni = 0; ni < 2; ++ni) {
        int col = n0 + wn + ni * 16 + lr;
#pragma unroll
        for (int r = 0; r < 4; ++r) {
          int row = m0 + wm + mi * 16 + lq * 4 + r;
          if (row < M) P[(size_t)row * N + col] = acc[mi][ni][r];
        }
      }
  } else {
    float f = alphaPtr ? tanhf(alphaPtr[0]) : 1.0f;
#pragma unroll
    for (int mi = 0; mi < 2; ++mi)
#pragma unroll
      for (int ni = 0; ni < 2; ++ni) {
        int col = n0 + wn + ni * 16 + lr;
        float bv = bias ? bias[col] : 0.f;
#pragma unroll
        for (int r = 0; r < 4; ++r) {
          int row = m0 + wm + mi * 16 + lq * 4 + r;
          if (row < M) {
            float val = acc[mi][ni][r] + bv;
            if (res) val = res[(size_t)row * N + col] + f * val;
            if (Out) Out[(size_t)row * N + col] = val;
            if (Ob)  Ob[(size_t)row * N + col] = f2b(val);
          }
        }
      }
  }
}

// ---------------- split-K reduce epilogue ----------------------------------
__global__ __launch_bounds__(256)
void splitk_epi(const float* __restrict__ Part, int nz, float* __restrict__ Out,
                ushort_t* __restrict__ Ob, int MN, int N,
                const float* __restrict__ bias, const float* __restrict__ res,
                const float* __restrict__ alphaPtr) {
  int idx = (blockIdx.x * 256 + threadIdx.x) * 4;
  if (idx >= MN) return;
  float f = alphaPtr ? tanhf(alphaPtr[0]) : 1.0f;
  float v[4] = {0.f, 0.f, 0.f, 0.f};
  for (int z = 0; z < nz; ++z) {
    float4 a = *(const float4*)&Part[(size_t)z * MN + idx];
    v[0] += a.x; v[1] += a.y; v[2] += a.z; v[3] += a.w;
  }
  if (bias) {
    int col = idx % N;
    float4 bb = *(const float4*)&bias[col];
    v[0] += bb.x; v[1] += bb.y; v[2] += bb.z; v[3] += bb.w;
  }
  if (res) {
    float4 rr = *(const float4*)&res[idx];
    v[0] = rr.x + f * v[0]; v[1] = rr.y + f * v[1];
    v[2] = rr.z + f * v[2]; v[3] = rr.w + f * v[3];
  }
  if (Out) *(float4*)&Out[idx] = make_float4(v[0], v[1], v[2], v[3]);
  if (Ob) {
    ushort4 o;
    o.x = f2b(v[0]); o.y = f2b(v[1]); o.z = f2b(v[2]); o.w = f2b(v[3]);
    *(ushort4*)&Ob[idx] = o;
  }
}

// ---------------- wo-epilogue (optional) + double layernorm ---------------
// nz>0: xv = xres + tanh(alpha)*(sum(Part)+bias), write x1. nz==0: xv = xres
// (already final; bias/Part unused). Then double LN -> hh.
__global__ __launch_bounds__(256)
void woepi_ln_kernel(const float* __restrict__ Part, int nz,
                     const float* __restrict__ bias, const float* __restrict__ xres,
                     const float* __restrict__ alphaPtr, float* __restrict__ x1,
                     const float* __restrict__ g1, const float* __restrict__ b1,
                     const float* __restrict__ g2, const float* __restrict__ b2,
                     ushort_t* __restrict__ hh) {
  __shared__ float sh[4];
  int row = blockIdx.x;
  float f = tanhf(alphaPtr[0]);
  float v[3];
#pragma unroll
  for (int j = 0; j < 3; ++j) {
    int c = threadIdx.x + j * 256;
    float xv;
    if (nz > 0) {
      float s = 0.f;
      for (int z = 0; z < nz; ++z) s += Part[(size_t)z * MNX + (size_t)row * C_DIM + c];
      s += bias[c];
      xv = xres[(size_t)row * C_DIM + c] + f * s;
      x1[(size_t)row * C_DIM + c] = xv;
    } else {
      xv = xres[(size_t)row * C_DIM + c];
    }
    v[j] = xv;
  }
  float mean = block_sum(v[0] + v[1] + v[2], sh) * (1.f / C_DIM);
  float sq = 0.f;
#pragma unroll
  for (int j = 0; j < 3; ++j) { float d = v[j] - mean; sq += d * d; }
  float rstd = rsqrtf(block_sum(sq, sh) * (1.f / C_DIM) + 1e-5f);
  float y[3];
#pragma unroll
  for (int j = 0; j < 3; ++j) {
    int c = threadIdx.x + j * 256;
    y[j] = (v[j] - mean) * rstd * g1[c] + b1[c];
  }
  float mean2 = block_sum(y[0] + y[1] + y[2], sh) * (1.f / C_DIM);
  sq = 0.f;
#pragma unroll
  for (int j = 0; j < 3; ++j) { float d = y[j] - mean2; sq += d * d; }
  float rstd2 = rsqrtf(block_sum(sq, sh) * (1.f / C_DIM) + 1e-5f);
#pragma unroll
  for (int j = 0; j < 3; ++j) {
    int c = threadIdx.x + j * 256;
    hh[(size_t)row * C_DIM + c] = f2b((y[j] - mean2) * rstd2 * g2[c] + b2[c]);
  }
}

// ---------------- V transpose: strided bf16 [key][64] -> Vt [dv][Nkp] -----
// Handles self (blocks x < xbreak) and cross (x >= xbreak) in one launch.
__global__ __launch_bounds__(256)
void vtrans_kernel(const ushort_t* __restrict__ V, ushort_t* __restrict__ Vt,
                   int rows_per_b, int stride, int Nk, int Nkp,
                   const ushort_t* __restrict__ V2, ushort_t* __restrict__ Vt2,
                   int rows2, int stride2, int Nk2, int Nkp2, int xbreak) {
  __shared__ ushort_t tile[64][68];
  int bx = blockIdx.x;
  if (bx >= xbreak) {
    bx -= xbreak;
    V = V2; Vt = Vt2; rows_per_b = rows2; stride = stride2; Nk = Nk2; Nkp = Nkp2;
  }
  int k0 = bx * 64;
  int h = blockIdx.y, b = blockIdx.z;
  int t = threadIdx.x;
#pragma unroll
  for (int p = 0; p < 4; ++p) {
    int r = p * 16 + (t >> 4), c = (t & 15) * 4;
    int key = k0 + r;
    ushort4 u = make_ushort4(0, 0, 0, 0);
    if (key < Nk)
      u = *(const ushort4*)&V[((size_t)(b * rows_per_b + key)) * stride + h * 64 + c];
    *(ushort4*)&tile[r][c] = u;
  }
  __syncthreads();
  size_t base = ((size_t)(b * 12 + h)) * 64 * Nkp;
#pragma unroll
  for (int p = 0; p < 4; ++p) {
    int dv = p * 16 + (t >> 4), kc = (t & 15) * 4;
    ushort4 u;
    u.x = tile[kc + 0][dv]; u.y = tile[kc + 1][dv];
    u.z = tile[kc + 2][dv]; u.w = tile[kc + 3][dv];
    *(ushort4*)&Vt[base + (size_t)dv * Nkp + k0 + kc] = u;
  }
}

// ---------------- MFMA flash attention (static-max, in-kernel normalize) ---
__global__ __launch_bounds__(256)
void attn_mfma(const ushort_t* __restrict__ Q, const ushort_t* __restrict__ K,
               const ushort_t* __restrict__ Vt, ushort_t* __restrict__ O,
               int q_rows_per_b, int kv_rows_per_b, int Nk, int Nkp,
               int qstride, int kstride) {
  __shared__ ushort_t sQ[4096];
  __shared__ ushort_t sK[2][4096];
  __shared__ ushort_t sV[2][4096];
  __shared__ ushort_t sP[4][1024];
  const float scale = 0.18033688011112042f;   // 1/8 * log2(e)
  const float M0 = 16.0f;
  int t = threadIdx.x;
  int w = t >> 6, ln = t & 63;
  int col = ln & 15, quad = ln >> 4;
  int b = blockIdx.z;
  int h = blockIdx.y, q0 = blockIdx.x * 64;
  size_t vt_base = ((size_t)(b * 12 + h)) * 64 * Nkp;
  int ntiles = Nkp >> 6;

#define STAGE_KV(kt_, bb_)                                                    \
  do {                                                                        \
    _Pragma("unroll") for (int s = 0; s < 2; ++s) {                           \
      int key = (kt_) * 64 + w * 16 + (ln >> 2);                              \
      g2lds16(K + (size_t)(b * kv_rows_per_b + key) * kstride                 \
                + h * 64 + s * 32 + (ln & 3) * 8,                             \
              (char*)sK[bb_] + s * 4096 + w * 1024);                          \
      int dv = w * 16 + (ln >> 2);                                            \
      g2lds16(Vt + vt_base + (size_t)dv * Nkp                                 \
                + (kt_) * 64 + s * 32 + (ln & 3) * 8,                         \
              (char*)sV[bb_] + s * 4096 + w * 1024);                          \
    }                                                                         \
  } while (0)

#pragma unroll
  for (int s = 0; s < 2; ++s) {
    int r = q0 + w * 16 + (ln >> 2);
    g2lds16(Q + (size_t)(b * q_rows_per_b + r) * qstride + h * 64 + s * 32 + (ln & 3) * 8,
            (char*)sQ + s * 4096 + w * 1024);
  }
  STAGE_KV(0, 0);
  __syncthreads();
  bf16x8 qa[2];
#pragma unroll
  for (int s = 0; s < 2; ++s)
    qa[s] = *(const bf16x8*)&sQ[s * 2048 + (w * 16 + col) * 32 + quad * 8];

  f32x4 oacc[4];
#pragma unroll
  for (int i = 0; i < 4; ++i) oacc[i] = (f32x4){0.f, 0.f, 0.f, 0.f};
  float l_i[4] = {0.f, 0.f, 0.f, 0.f};

  ushort_t* sPw = sP[w];
  int bb = 0;

  for (int kt = 0; kt < ntiles; ++kt) {
    if (kt + 1 < ntiles) STAGE_KV(kt + 1, bb ^ 1);

    f32x4 cs[4];
#pragma unroll
    for (int nblk = 0; nblk < 4; ++nblk) {
      cs[nblk] = (f32x4){0.f, 0.f, 0.f, 0.f};
#pragma unroll
      for (int s = 0; s < 2; ++s) {
        bf16x8 kb = *(const bf16x8*)&sK[bb][s * 2048 + (nblk * 16 + col) * 32 + quad * 8];
        cs[nblk] = __builtin_amdgcn_mfma_f32_16x16x32_bf16(qa[s], kb, cs[nblk], 0, 0, 0);
      }
    }
    if (kt * 64 + 64 > Nk) {
#pragma unroll
      for (int nblk = 0; nblk < 4; ++nblk) {
        bool valid = (kt * 64 + nblk * 16 + col) < Nk;
#pragma unroll
        for (int r = 0; r < 4; ++r)
          cs[nblk][r] = valid ? cs[nblk][r] : -1e30f;
      }
    }
#pragma unroll
    for (int r = 0; r < 4; ++r) {
      int row = quad * 4 + r;
#pragma unroll
      for (int nblk = 0; nblk < 4; ++nblk) {
        float p = exp2f(fmaf(cs[nblk][r], scale, -M0));
        l_i[r] += p;
        int kin = (nblk & 1) * 16 + col;
        sPw[(nblk >> 1) * 512 + row * 32 + (kin ^ (quad << 3))] = f2b(p);
      }
    }
#pragma unroll
    for (int s = 0; s < 2; ++s) {
      bf16x8 pa = *(const bf16x8*)&sPw[s * 512 + col * 32 + ((quad ^ ((col >> 2) & 3)) << 3)];
#pragma unroll
      for (int nblk = 0; nblk < 4; ++nblk) {
        bf16x8 vb = *(const bf16x8*)&sV[bb][s * 2048 + (nblk * 16 + col) * 32 + quad * 8];
        oacc[nblk] = __builtin_amdgcn_mfma_f32_16x16x32_bf16(pa, vb, oacc[nblk], 0, 0, 0);
      }
    }
    if (kt + 1 < ntiles) __syncthreads();
    bb ^= 1;
  }
#undef STAGE_KV

#pragma unroll
  for (int r = 0; r < 4; ++r) {
    float ps = l_i[r];
#pragma unroll
    for (int o = 1; o < 16; o <<= 1) ps += __shfl_xor(ps, o);
    int qglob = b * N_DIM + q0 + w * 16 + quad * 4 + r;
    float inv = 1.f / ps;
#pragma unroll
    for (int nblk = 0; nblk < 4; ++nblk)
      O[(size_t)qglob * C_DIM + h * 64 + nblk * 16 + col] = f2b(oacc[nblk][r] * inv);
  }
}

// ---------------------------------------------------------------------------
extern "C" void kernel_launch(void* const* d_in, const int* in_sizes, int n_in,
                              void* d_out, int out_size, void* d_ws, size_t ws_size,
                              hipStream_t stream) {
  const float* x        = (const float*)d_in[0];
  const float* enc      = (const float*)d_in[1];
  const float* ln1_g    = (const float*)d_in[2];
  const float* ln1_b    = (const float*)d_in[3];
  const float* ln2_g    = (const float*)d_in[4];
  const float* ln2_b    = (const float*)d_in[5];
  const float* sa_wq    = (const float*)d_in[6];
  const float* sa_wk    = (const float*)d_in[7];
  const float* sa_wv    = (const float*)d_in[8];
  const float* sa_wo    = (const float*)d_in[9];
  const float* sa_wo_b  = (const float*)d_in[10];
  const float* ff_ln_g  = (const float*)d_in[11];
  const float* ff_ln_b  = (const float*)d_in[12];
  const float* ff_w1    = (const float*)d_in[13];
  const float* ff_w2    = (const float*)d_in[14];
  const float* a_attn   = (const float*)d_in[15];
  const float* a_dense  = (const float*)d_in[16];
  const float* ca_wq    = (const float*)d_in[17];
  const float* ca_wk    = (const float*)d_in[18];
  const float* ca_wv    = (const float*)d_in[19];
  const float* ca_wo    = (const float*)d_in[20];
  const float* ca_wo_b  = (const float*)d_in[21];

  char* ws = (char*)d_ws;
  float*    x1     = (float*)(ws + WX1);
  float*    x2     = (float*)(ws + WX2);
  ushort_t* qkv_b  = (ushort_t*)(ws + WQKV);
  ushort_t* q2b    = (ushort_t*)(ws + WQKV);
  ushort_t* kv2b   = (ushort_t*)(ws + WQKV + 3145728u);
  ushort_t* comb_b = (ushort_t*)(ws + WBB1);
  ushort_t* attn_b = (ushort_t*)(ws + WATTN);
  ushort_t* g_b    = (ushort_t*)(ws + WG);
  ushort_t* hh     = (ushort_t*)(ws + WS1);
  ushort_t* x2b    = (ushort_t*)(ws + WS1);
  ushort_t* text_b = (ushort_t*)(ws + WTEXT);
  ushort_t* attn2b = (ushort_t*)(ws + WATT2);
  ushort_t* wqkv_t = (ushort_t*)(ws + WWQKV);
  ushort_t* wo_t   = (ushort_t*)(ws + WWO);
  ushort_t* w1_t   = (ushort_t*)(ws + WW1);
  ushort_t* w2_t   = (ushort_t*)(ws + WW2);
  ushort_t* cawq_t = (ushort_t*)(ws + WCAWQ);
  ushort_t* cakv_t = (ushort_t*)(ws + WCAKV);
  ushort_t* cawo_t = (ushort_t*)(ws + WCAWO);
  ushort_t* vt1    = (ushort_t*)(ws + WVT1);
  ushort_t* vt2    = (ushort_t*)(ws + WVT2);
  float* part = (float*)(ws + WPART);
  float* out = (float*)d_out;

  const int Mc = B_DIM * NC_DIM;   // 2080
  const int Mx = B_DIM * N_DIM;    // 2048
  const int Mt = B_DIM * TEXT_LEN; // 154

  // ---- launch 1: weight transposes + LN/concat + text gather ----
  WtDesc wd;
  const float* srcs[10] = {sa_wq, sa_wk, sa_wv, sa_wo, ca_wq, ca_wk, ca_wv, ca_wo, ff_w1, ff_w2};
  ushort_t* dsts[10] = {wqkv_t, wqkv_t + 589824, wqkv_t + 2 * 589824, wo_t,
                        cawq_t, cakv_t, cakv_t + 589824, cawo_t, w1_t, w2_t};
  int Ks[10] = {768, 768, 768, 768, 768, 768, 768, 768, 768, 3072};
  int Ns[10] = {768, 768, 768, 768, 768, 768, 768, 768, 6144, 768};
  int total = 0;
  for (int j = 0; j < 10; ++j) {
    wd.src[j] = srcs[j]; wd.dst[j] = dsts[j];
    wd.K[j] = Ks[j]; wd.N[j] = Ns[j];
    wd.tilesX[j] = Ns[j] / 64;
    wd.ileave[j] = (j == 8) ? 1 : 0;
    wd.start[j] = total;
    total += (Ns[j] / 64) * (Ks[j] / 64);
  }
  wd.start[10] = total;   // 2880

  prep_kernel<<<total + Mc + Mt, 256, 0, stream>>>(
      wd, x, enc, ln1_g, ln1_b, comb_b, text_b);
  // ---- launch 2: qkv GEMM (y<33) + kv GEMM (y>=33, x<24) ----
  gemm64<<<dim3(36, 36, 1), 256, 0, stream>>>(
      comb_b, wqkv_t, nullptr, qkv_b, nullptr, Mc, 2304, 768, 768,
      nullptr, nullptr, nullptr,
      text_b, cakv_t, kv2b, Mt, 1536, 33);
  // ---- launch 3: V transposes (self x<17, cross x>=17) ----
  vtrans_kernel<<<dim3(19, 12, B_DIM), 256, 0, stream>>>(
      qkv_b + 1536, vt1, NC_DIM, 2304, NC_DIM, 1088,
      kv2b + 768, vt2, TEXT_LEN, 1536, TEXT_LEN, 128, 17);
  // ---- self-attn: single pass, in-kernel normalize (no merge) ----
  attn_mfma<<<dim3(N_DIM / 64, 12, B_DIM), 256, 0, stream>>>(
      qkv_b + 0, qkv_b + 768, vt1, attn_b,
      NC_DIM, NC_DIM, NC_DIM, 1088, 2304, 2304);
  // ---- wo: gemm64 z=1, fused bias+res+alpha, fp32 x1 out (no slabs) ----
  gemm64<<<dim3(12, 32, 1), 256, 0, stream>>>(
      attn_b, wo_t, x1, nullptr, nullptr, Mx, 768, 768, 768,
      sa_wo_b, x, a_attn,
      nullptr, nullptr, nullptr, 0, 0, 0);
  // ---- double layernorm from x1 -> hh ----
  woepi_ln_kernel<<<Mx, 256, 0, stream>>>(
      nullptr, 0, nullptr, x1, a_attn, x1, ln2_g, ln2_b, ff_ln_g, ff_ln_b, hh);
  // ---- ff1 + fused GEGLU (128-tile, interleaved w1) -> g_b [2048][3072] ----
  gemm_bf16<<<dim3(48, 16), 256, 0, stream>>>(
      hh, w1_t, nullptr, g_b, Mx, 6144, 768);
  // ---- ff2: gemm64 split-K z=2 (768 blocks x 24 iters) -> splitk_epi ----
  gemm64<<<dim3(12, 32, 2), 256, 0, stream>>>(
      g_b, w2_t, nullptr, nullptr, part, Mx, 768, 3072, 1536,
      nullptr, nullptr, nullptr,
      nullptr, nullptr, nullptr, 0, 0, 0);
  splitk_epi<<<MNX / 1024, 256, 0, stream>>>(
      part, 2, x2, x2b, MNX, 768, nullptr, x1, a_dense);
  // ---- q2: gemm64 z=1, direct bf16 out ----
  gemm64<<<dim3(12, 32, 1), 256, 0, stream>>>(
      x2b, cawq_t, nullptr, q2b, nullptr, Mx, 768, 768, 768,
      nullptr, nullptr, nullptr,
      nullptr, nullptr, nullptr, 0, 0, 0);
  // ---- cross-attn: in-kernel normalize ----
  attn_mfma<<<dim3(N_DIM / 64, 12, B_DIM), 256, 0, stream>>>(
      q2b, kv2b + 0, vt2, attn2b,
      N_DIM, TEXT_LEN, TEXT_LEN, 128, 768, 1536);
  // ---- final: gemm64 z=1, fused bias+residual, fp32 out ----
  gemm64<<<dim3(12, 32, 1), 256, 0, stream>>>(
      attn2b, cawo_t, out, nullptr, nullptr, Mx, 768, 768, 768,
      ca_wo_b, x2, nullptr,
      nullptr, nullptr, nullptr, 0, 0, 0);
}

// Round 6
// 301.575 us; speedup vs baseline: 1.0174x; 1.0174x over previous
//
#include <hip/hip_runtime.h>
#include <hip/hip_bf16.h>
#include <math.h>

// ---------------------------------------------------------------------------
// FaceAttnProcessor forward. R15 (= R14 + pair-in-lane GEGLU):
// - w1 transpose remap: a-col c -> dstrow (c>>4)*32+(c&15); gate-col c ->
//   same +16. In the 128-tile GEMM, acc[mi][2p] (a) and acc[mi][2p+1] (gate)
//   of the SAME lane then form an output pair: GEGLU epilogue loses all 64
//   __shfl_xor, half the erff calls, and the (lr&1) divergence.
//   Output col c = (n0+wn)/2 + p*16 + lr  (verified bijective, coalesced).
// - everything else identical to R14 (12 launches).
// B=2, N=1024, C=768, H=12, INNER=3072.
// ---------------------------------------------------------------------------

#define C_DIM 768
#define B_DIM 2
#define N_DIM 1024
#define NC_DIM 1040
#define L_DIM 93
#define TEXT_LEN 77
#define INNER 3072
#define MNX 1572864   // 2048*768

typedef unsigned short ushort_t;
typedef __bf16 bf16x8 __attribute__((ext_vector_type(8)));
typedef float f32x4 __attribute__((ext_vector_type(4)));

__device__ __forceinline__ ushort_t f2b(float f) {
  __hip_bfloat16 h = __float2bfloat16(f);
  return *(ushort_t*)&h;
}
__device__ __forceinline__ float b2f(ushort_t u) {
  __hip_bfloat16 h = *(__hip_bfloat16*)&u;
  return __bfloat162float(h);
}

__device__ __forceinline__ void g2lds16(const void* g, void* l) {
  __builtin_amdgcn_global_load_lds(
      (const __attribute__((address_space(1))) unsigned int*)g,
      (__attribute__((address_space(3))) unsigned int*)l, 16, 0, 0);
}

// ---------------- workspace map (byte offsets) ----------------------------
#define WX1    0u           // fp32 x1 (2048*768)
#define WX2    6291456u     // fp32 x2
#define WQKV   12582912u    // u16 qkv_b [2080][2304]; later q2b/kv2b
#define WBB1   22167552u    // comb_b / split-K partial slabs (<=4)
#define WG     47333376u    // attn_b (phase A) / g_b (phase C)
#define WS1    59916288u    // u16 hh / x2b [2048][768]
#define WTEXT  63062016u    // u16 text_b [154][768]
#define WATT2  63298560u    // u16 attn2b [2048][768]
#define WWQKV  66444288u    // u16 wqkv_t [2304][768]
#define WWO    69983232u    // u16 wo_t   [768][768]
#define WW1    71162880u    // u16 w1_t   [6144][768] (pair-in-lane a/gate rows)
#define WW2    80600064u    // u16 w2_t   [768][3072]
#define WCAWQ  85318656u    // u16 cawq_t [768][768]
#define WCAKV  86498304u    // u16 cakv_t [1536][768]
#define WCAWO  88857600u    // u16 cawo_t [768][768]
#define WVT1   90037248u    // u16 Vt self  [2][12][64][1088]
#define WVT2   93379584u    // u16 Vt cross [2][12][64][128]
#define WATTN  (WG + 524288u)       // u16 attn_b (dead before g_b written)
#define WPART  WBB1                 // fp32 split-K partials (<=4 slabs = 25.2MB)
// end: 93,772,800 B

// ---------------- block reduction (256 threads = 4 waves) -----------------
__device__ __forceinline__ float block_sum(float v, float* sh) {
#pragma unroll
  for (int o = 32; o > 0; o >>= 1) v += __shfl_down(v, o);
  int lane = threadIdx.x & 63, w = threadIdx.x >> 6;
  if (lane == 0) sh[w] = v;
  __syncthreads();
  float r = sh[0] + sh[1] + sh[2] + sh[3];
  __syncthreads();
  return r;
}

// ---------------- prep: weight transposes + LN/concat + text gather -------
struct WtDesc {
  const float* src[10];
  ushort_t*    dst[10];
  int K[10];
  int N[10];
  int tilesX[10];
  int ileave[10];
  int start[11];
};

__global__ __launch_bounds__(256)
void prep_kernel(WtDesc d,
                 const float* __restrict__ x, const float* __restrict__ enc,
                 const float* __restrict__ g, const float* __restrict__ b,
                 ushort_t* __restrict__ comb, ushort_t* __restrict__ text) {
  __shared__ float tile[64][65];
  int bid = blockIdx.x;
  int nwt = d.start[10];
  if (bid >= nwt) {
    // ---- LN(x)/LN(face) -> comb, or text gather ----
    int r = bid - nwt;
    if (r >= B_DIM * NC_DIM) {
      int i = r - B_DIM * NC_DIM;
      int bb = i / TEXT_LEN, j = i % TEXT_LEN;
      const float* src = enc + ((size_t)bb * L_DIM + j) * C_DIM;
      ushort_t* dst = text + (size_t)i * C_DIM;
#pragma unroll
      for (int l = 0; l < 3; ++l) {
        int c = threadIdx.x + l * 256;
        dst[c] = f2b(src[c]);
      }
      return;
    }
    float* sh = &tile[0][0];
    int bb = r / NC_DIM, i = r % NC_DIM;
    const float* src = (i < N_DIM)
        ? (x   + ((size_t)bb * N_DIM + i) * C_DIM)
        : (enc + ((size_t)bb * L_DIM + TEXT_LEN + (i - N_DIM)) * C_DIM);
    float v[3];
#pragma unroll
    for (int j = 0; j < 3; ++j) v[j] = src[threadIdx.x + j * 256];
    float mean = block_sum(v[0] + v[1] + v[2], sh) * (1.f / C_DIM);
    float sq = 0.f;
#pragma unroll
    for (int j = 0; j < 3; ++j) { float dd = v[j] - mean; sq += dd * dd; }
    float rstd = rsqrtf(block_sum(sq, sh) * (1.f / C_DIM) + 1e-5f);
    ushort_t* dst = comb + (size_t)r * C_DIM;
#pragma unroll
    for (int j = 0; j < 3; ++j) {
      int c = threadIdx.x + j * 256;
      dst[c] = f2b((v[j] - mean) * rstd * g[c] + b[c]);
    }
    return;
  }
  // ---- weight cast+transpose ----
  int j = 0;
  while (j < 9 && bid >= d.start[j + 1]) ++j;
  int ti = bid - d.start[j];
  int K = d.K[j], N = d.N[j];
  int n0 = (ti % d.tilesX[j]) * 64, k0 = (ti / d.tilesX[j]) * 64;
  const float* in = d.src[j];
  ushort_t* out = d.dst[j];
  int il = d.ileave[j];
  int t = threadIdx.x;
#pragma unroll
  for (int p = 0; p < 16; ++p) {
    int idx = t + p * 256;
    int r = idx >> 6, c = idx & 63;
    tile[r][c] = in[(size_t)(k0 + r) * N + n0 + c];
  }
  __syncthreads();
#pragma unroll
  for (int p = 0; p < 16; ++p) {
    int idx = t + p * 256;
    int r = idx >> 6, c = idx & 63;
    int nrow = n0 + r;
    int dstrow;
    if (il) {
      // pair-in-lane GEGLU layout: a-col c -> (c>>4)*32+(c&15); gate +16
      int cc = (nrow < INNER) ? nrow : (nrow - INNER);
      dstrow = ((cc >> 4) << 5) + (cc & 15) + ((nrow < INNER) ? 0 : 16);
    } else {
      dstrow = nrow;
    }
    out[(size_t)dstrow * K + k0 + c] = f2b(tile[c][r]);
  }
}

// ---------------- bf16 MFMA GEMM, 128x128 tile -----------------------------
// Paths: Og!=null -> fused GEGLU (pair-in-lane a/gate rows); else bf16 Ob.
__global__ __launch_bounds__(256)
void gemm_bf16(const ushort_t* __restrict__ A, const ushort_t* __restrict__ Bt,
               ushort_t* __restrict__ Ob, ushort_t* __restrict__ Og,
               int M, int N, int K) {
  __shared__ ushort_t sA[2][128 * 32];
  __shared__ ushort_t sB[2][128 * 32];
  int t = threadIdx.x;
  int w = t >> 6, ln = t & 63;
  int m0 = blockIdx.y * 128, n0 = blockIdx.x * 128;
  int wm = (w >> 1) * 64, wn = (w & 1) * 64;
  int lr = ln & 15, lq = ln >> 4;
  int seg_r = ln >> 2, seg_c = (ln & 3) * 8;

  f32x4 acc[4][4];
#pragma unroll
  for (int mi = 0; mi < 4; ++mi)
#pragma unroll
    for (int ni = 0; ni < 4; ++ni) acc[mi][ni] = (f32x4){0.f, 0.f, 0.f, 0.f};

#define STAGE(k0_, buf_)                                                     \
  do {                                                                       \
    _Pragma("unroll") for (int l = 0; l < 2; ++l) {                          \
      int s = w * 2 + l;                                                     \
      int arow = m0 + s * 16 + seg_r;                                        \
      arow = arow < M ? arow : M - 1;                                        \
      g2lds16(A + (size_t)arow * K + (k0_) + seg_c, &sA[buf_][s * 512]);     \
      int nrow = n0 + s * 16 + seg_r;                                        \
      g2lds16(Bt + (size_t)nrow * K + (k0_) + seg_c, &sB[buf_][s * 512]);    \
    }                                                                        \
  } while (0)

  STAGE(0, 0);
  __syncthreads();
  int cur = 0;
  for (int k0 = 0; k0 < K; k0 += 32) {
    if (k0 + 32 < K) STAGE(k0 + 32, cur ^ 1);
    bf16x8 af[4], bfr[4];
#pragma unroll
    for (int mi = 0; mi < 4; ++mi)
      af[mi] = *(const bf16x8*)&sA[cur][(wm + mi * 16 + lr) * 32 + lq * 8];
#pragma unroll
    for (int ni = 0; ni < 4; ++ni)
      bfr[ni] = *(const bf16x8*)&sB[cur][(wn + ni * 16 + lr) * 32 + lq * 8];
#pragma unroll
    for (int mi = 0; mi < 4; ++mi)
#pragma unroll
      for (int ni = 0; ni < 4; ++ni)
        acc[mi][ni] = __builtin_amdgcn_mfma_f32_16x16x32_bf16(
            af[mi], bfr[ni], acc[mi][ni], 0, 0, 0);
    __syncthreads();
    cur ^= 1;
  }
#undef STAGE

  if (Og) {
    // pair-in-lane GEGLU: acc[mi][2p] = a, acc[mi][2p+1] = gate, same lane.
    // output col c = (n0+wn)/2 + p*16 + lr
    int cbase = ((n0 + wn) >> 1) + lr;
#pragma unroll
    for (int mi = 0; mi < 4; ++mi)
#pragma unroll
      for (int p = 0; p < 2; ++p) {
        int c = cbase + p * 16;
#pragma unroll
        for (int r = 0; r < 4; ++r) {
          float a = acc[mi][2 * p][r];
          float gate = acc[mi][2 * p + 1][r];
          float ge = 0.5f * gate * (1.f + erff(gate * 0.70710678118654752f));
          int row = m0 + wm + mi * 16 + lq * 4 + r;
          Og[(size_t)row * INNER + c] = f2b(a * ge);
        }
      }
  } else {
#pragma unroll
    for (int mi = 0; mi < 4; ++mi)
#pragma unroll
      for (int ni = 0; ni < 4; ++ni) {
        int col = n0 + wn + ni * 16 + lr;
#pragma unroll
        for (int r = 0; r < 4; ++r) {
          int row = m0 + wm + mi * 16 + lq * 4 + r;
          if (row < M) Ob[(size_t)row * N + col] = f2b(acc[mi][ni][r]);
        }
      }
  }
}

// ---------------- bf16 MFMA GEMM, 64x64 tile, BK=64, optional split-K ------
// 4 waves, each 32x32 subtile (2x2 MFMA). grid.z = K/Ksplit splits;
// Part!=null: fp32 partial slabs; else fused bias/res/alpha epilogue.
// Optional second problem: blocks with blockIdx.y >= ybreak compute
// {A2,Bt2}->Ob2 (bf16 out).
__global__ __launch_bounds__(256)
void gemm64(const ushort_t* __restrict__ A, const ushort_t* __restrict__ Bt,
            float* __restrict__ Out, ushort_t* __restrict__ Ob,
            float* __restrict__ Part,
            int M, int N, int K, int Ksplit,
            const float* __restrict__ bias, const float* __restrict__ res,
            const float* __restrict__ alphaPtr,
            const ushort_t* __restrict__ A2, const ushort_t* __restrict__ Bt2,
            ushort_t* __restrict__ Ob2, int M2, int N2, int ybreak) {
  __shared__ ushort_t sA[2][4096];   // [buf][s*2048 + row*32 + k]
  __shared__ ushort_t sB[2][4096];
  int by = blockIdx.y;
  if (A2 && by >= ybreak) {
    if ((int)blockIdx.x * 64 >= N2) return;
    A = A2; Bt = Bt2; Ob = Ob2; M = M2; N = N2;
    Out = nullptr; Part = nullptr; bias = nullptr; res = nullptr; alphaPtr = nullptr;
    by -= ybreak;
  }
  int t = threadIdx.x;
  int w = t >> 6, ln = t & 63;
  int m0 = by * 64, n0 = blockIdx.x * 64;
  int wm = (w >> 1) * 32, wn = (w & 1) * 32;
  int lr = ln & 15, lq = ln >> 4;
  int srow = (w & 1) * 32 + (ln >> 2);        // staging row (+ i*16)
  int skoff = (w >> 1) * 32 + (ln & 3) * 8;   // staging k offset
  int kbeg = blockIdx.z * Ksplit;
  int kend = kbeg + Ksplit; if (kend > K) kend = K;

  f32x4 acc[2][2];
#pragma unroll
  for (int mi = 0; mi < 2; ++mi)
#pragma unroll
    for (int ni = 0; ni < 2; ++ni) acc[mi][ni] = (f32x4){0.f, 0.f, 0.f, 0.f};

#define STG64(k0_, buf_)                                                      \
  do {                                                                        \
    _Pragma("unroll") for (int i = 0; i < 2; ++i) {                           \
      int ar = m0 + srow + i * 16; ar = ar < M ? ar : M - 1;                  \
      g2lds16(A + (size_t)ar * K + (k0_) + skoff,                             \
              (char*)sA + (buf_) * 8192 + w * 2048 + i * 1024);               \
      int nr = n0 + srow + i * 16;                                            \
      g2lds16(Bt + (size_t)nr * K + (k0_) + skoff,                            \
              (char*)sB + (buf_) * 8192 + w * 2048 + i * 1024);               \
    }                                                                         \
  } while (0)

  STG64(kbeg, 0);
  __syncthreads();
  int cur = 0;
  for (int k0 = kbeg; k0 < kend; k0 += 64) {
    if (k0 + 64 < kend) STG64(k0 + 64, cur ^ 1);
#pragma unroll
    for (int s = 0; s < 2; ++s) {
      bf16x8 a0 = *(const bf16x8*)&sA[cur][s * 2048 + (wm + lr) * 32 + lq * 8];
      bf16x8 a1 = *(const bf16x8*)&sA[cur][s * 2048 + (wm + 16 + lr) * 32 + lq * 8];
      bf16x8 b0 = *(const bf16x8*)&sB[cur][s * 2048 + (wn + lr) * 32 + lq * 8];
      bf16x8 b1 = *(const bf16x8*)&sB[cur][s * 2048 + (wn + 16 + lr) * 32 + lq * 8];
      acc[0][0] = __builtin_amdgcn_mfma_f32_16x16x32_bf16(a0, b0, acc[0][0], 0, 0, 0);
      acc[0][1] = __builtin_amdgcn_mfma_f32_16x16x32_bf16(a0, b1, acc[0][1], 0, 0, 0);
      acc[1][0] = __builtin_amdgcn_mfma_f32_16x16x32_bf16(a1, b0, acc[1][0], 0, 0, 0);
      acc[1][1] = __builtin_amdgcn_mfma_f32_16x16x32_bf16(a1, b1, acc[1][1], 0, 0, 0);
    }
    __syncthreads();
    cur ^= 1;
  }
#undef STG64

  if (Part) {
    float* P = Part + (size_t)blockIdx.z * M * N;
#pragma unroll
    for (int mi = 0; mi < 2; ++mi)
#pragma unroll
      for (int ni = 0; ni < 2; ++ni) {
        int col = n0 + wn + ni * 16 + lr;
#pragma unroll
        for (int r = 0; r < 4; ++r) {
          int row = m0 + wm + mi * 16 + lq * 4 + r;
          if (row < M) P[(size_t)row * N + col] = acc[mi][ni][r];
        }
      }
  } else {
    float f = alphaPtr ? tanhf(alphaPtr[0]) : 1.0f;
#pragma unroll
    for (int mi = 0; mi < 2; ++mi)
#pragma unroll
      for (int ni = 0; ni < 2; ++ni) {
        int col = n0 + wn + ni * 16 + lr;
        float bv = bias ? bias[col] : 0.f;
#pragma unroll
        for (int r = 0; r < 4; ++r) {
          int row = m0 + wm + mi * 16 + lq * 4 + r;
          if (row < M) {
            float val = acc[mi][ni][r] + bv;
            if (res) val = res[(size_t)row * N + col] + f * val;
            if (Out) Out[(size_t)row * N + col] = val;
            if (Ob)  Ob[(size_t)row * N + col] = f2b(val);
          }
        }
      }
  }
}

// ---------------- split-K reduce epilogue ----------------------------------
__global__ __launch_bounds__(256)
void splitk_epi(const float* __restrict__ Part, int nz, float* __restrict__ Out,
                ushort_t* __restrict__ Ob, int MN, int N,
                const float* __restrict__ bias, const float* __restrict__ res,
                const float* __restrict__ alphaPtr) {
  int idx = (blockIdx.x * 256 + threadIdx.x) * 4;
  if (idx >= MN) return;
  float f = alphaPtr ? tanhf(alphaPtr[0]) : 1.0f;
  float v[4] = {0.f, 0.f, 0.f, 0.f};
  for (int z = 0; z < nz; ++z) {
    float4 a = *(const float4*)&Part[(size_t)z * MN + idx];
    v[0] += a.x; v[1] += a.y; v[2] += a.z; v[3] += a.w;
  }
  if (bias) {
    int col = idx % N;
    float4 bb = *(const float4*)&bias[col];
    v[0] += bb.x; v[1] += bb.y; v[2] += bb.z; v[3] += bb.w;
  }
  if (res) {
    float4 rr = *(const float4*)&res[idx];
    v[0] = rr.x + f * v[0]; v[1] = rr.y + f * v[1];
    v[2] = rr.z + f * v[2]; v[3] = rr.w + f * v[3];
  }
  if (Out) *(float4*)&Out[idx] = make_float4(v[0], v[1], v[2], v[3]);
  if (Ob) {
    ushort4 o;
    o.x = f2b(v[0]); o.y = f2b(v[1]); o.z = f2b(v[2]); o.w = f2b(v[3]);
    *(ushort4*)&Ob[idx] = o;
  }
}

// ---------------- wo-epilogue (optional) + double layernorm ---------------
// nz>0: xv = xres + tanh(alpha)*(sum(Part)+bias), write x1. nz==0: xv = xres
// (already final; bias/Part unused). Then double LN -> hh.
__global__ __launch_bounds__(256)
void woepi_ln_kernel(const float* __restrict__ Part, int nz,
                     const float* __restrict__ bias, const float* __restrict__ xres,
                     const float* __restrict__ alphaPtr, float* __restrict__ x1,
                     const float* __restrict__ g1, const float* __restrict__ b1,
                     const float* __restrict__ g2, const float* __restrict__ b2,
                     ushort_t* __restrict__ hh) {
  __shared__ float sh[4];
  int row = blockIdx.x;
  float f = tanhf(alphaPtr[0]);
  float v[3];
#pragma unroll
  for (int j = 0; j < 3; ++j) {
    int c = threadIdx.x + j * 256;
    float xv;
    if (nz > 0) {
      float s = 0.f;
      for (int z = 0; z < nz; ++z) s += Part[(size_t)z * MNX + (size_t)row * C_DIM + c];
      s += bias[c];
      xv = xres[(size_t)row * C_DIM + c] + f * s;
      x1[(size_t)row * C_DIM + c] = xv;
    } else {
      xv = xres[(size_t)row * C_DIM + c];
    }
    v[j] = xv;
  }
  float mean = block_sum(v[0] + v[1] + v[2], sh) * (1.f / C_DIM);
  float sq = 0.f;
#pragma unroll
  for (int j = 0; j < 3; ++j) { float d = v[j] - mean; sq += d * d; }
  float rstd = rsqrtf(block_sum(sq, sh) * (1.f / C_DIM) + 1e-5f);
  float y[3];
#pragma unroll
  for (int j = 0; j < 3; ++j) {
    int c = threadIdx.x + j * 256;
    y[j] = (v[j] - mean) * rstd * g1[c] + b1[c];
  }
  float mean2 = block_sum(y[0] + y[1] + y[2], sh) * (1.f / C_DIM);
  sq = 0.f;
#pragma unroll
  for (int j = 0; j < 3; ++j) { float d = y[j] - mean2; sq += d * d; }
  float rstd2 = rsqrtf(block_sum(sq, sh) * (1.f / C_DIM) + 1e-5f);
#pragma unroll
  for (int j = 0; j < 3; ++j) {
    int c = threadIdx.x + j * 256;
    hh[(size_t)row * C_DIM + c] = f2b((y[j] - mean2) * rstd2 * g2[c] + b2[c]);
  }
}

// ---------------- V transpose: strided bf16 [key][64] -> Vt [dv][Nkp] -----
// Handles self (blocks x < xbreak) and cross (x >= xbreak) in one launch.
__global__ __launch_bounds__(256)
void vtrans_kernel(const ushort_t* __restrict__ V, ushort_t* __restrict__ Vt,
                   int rows_per_b, int stride, int Nk, int Nkp,
                   const ushort_t* __restrict__ V2, ushort_t* __restrict__ Vt2,
                   int rows2, int stride2, int Nk2, int Nkp2, int xbreak) {
  __shared__ ushort_t tile[64][68];
  int bx = blockIdx.x;
  if (bx >= xbreak) {
    bx -= xbreak;
    V = V2; Vt = Vt2; rows_per_b = rows2; stride = stride2; Nk = Nk2; Nkp = Nkp2;
  }
  int k0 = bx * 64;
  int h = blockIdx.y, b = blockIdx.z;
  int t = threadIdx.x;
#pragma unroll
  for (int p = 0; p < 4; ++p) {
    int r = p * 16 + (t >> 4), c = (t & 15) * 4;
    int key = k0 + r;
    ushort4 u = make_ushort4(0, 0, 0, 0);
    if (key < Nk)
      u = *(const ushort4*)&V[((size_t)(b * rows_per_b + key)) * stride + h * 64 + c];
    *(ushort4*)&tile[r][c] = u;
  }
  __syncthreads();
  size_t base = ((size_t)(b * 12 + h)) * 64 * Nkp;
#pragma unroll
  for (int p = 0; p < 4; ++p) {
    int dv = p * 16 + (t >> 4), kc = (t & 15) * 4;
    ushort4 u;
    u.x = tile[kc + 0][dv]; u.y = tile[kc + 1][dv];
    u.z = tile[kc + 2][dv]; u.w = tile[kc + 3][dv];
    *(ushort4*)&Vt[base + (size_t)dv * Nkp + k0 + kc] = u;
  }
}

// ---------------- MFMA flash attention (static-max, in-kernel normalize) ---
__global__ __launch_bounds__(256)
void attn_mfma(const ushort_t* __restrict__ Q, const ushort_t* __restrict__ K,
               const ushort_t* __restrict__ Vt, ushort_t* __restrict__ O,
               int q_rows_per_b, int kv_rows_per_b, int Nk, int Nkp,
               int qstride, int kstride) {
  __shared__ ushort_t sQ[4096];
  __shared__ ushort_t sK[2][4096];
  __shared__ ushort_t sV[2][4096];
  __shared__ ushort_t sP[4][1024];
  const float scale = 0.18033688011112042f;   // 1/8 * log2(e)
  const float M0 = 16.0f;
  int t = threadIdx.x;
  int w = t >> 6, ln = t & 63;
  int col = ln & 15, quad = ln >> 4;
  int b = blockIdx.z;
  int h = blockIdx.y, q0 = blockIdx.x * 64;
  size_t vt_base = ((size_t)(b * 12 + h)) * 64 * Nkp;
  int ntiles = Nkp >> 6;

#define STAGE_KV(kt_, bb_)                                                    \
  do {                                                                        \
    _Pragma("unroll") for (int s = 0; s < 2; ++s) {                           \
      int key = (kt_) * 64 + w * 16 + (ln >> 2);                              \
      g2lds16(K + (size_t)(b * kv_rows_per_b + key) * kstride                 \
                + h * 64 + s * 32 + (ln & 3) * 8,                             \
              (char*)sK[bb_] + s * 4096 + w * 1024);                          \
      int dv = w * 16 + (ln >> 2);                                            \
      g2lds16(Vt + vt_base + (size_t)dv * Nkp                                 \
                + (kt_) * 64 + s * 32 + (ln & 3) * 8,                         \
              (char*)sV[bb_] + s * 4096 + w * 1024);                          \
    }                                                                         \
  } while (0)

#pragma unroll
  for (int s = 0; s < 2; ++s) {
    int r = q0 + w * 16 + (ln >> 2);
    g2lds16(Q + (size_t)(b * q_rows_per_b + r) * qstride + h * 64 + s * 32 + (ln & 3) * 8,
            (char*)sQ + s * 4096 + w * 1024);
  }
  STAGE_KV(0, 0);
  __syncthreads();
  bf16x8 qa[2];
#pragma unroll
  for (int s = 0; s < 2; ++s)
    qa[s] = *(const bf16x8*)&sQ[s * 2048 + (w * 16 + col) * 32 + quad * 8];

  f32x4 oacc[4];
#pragma unroll
  for (int i = 0; i < 4; ++i) oacc[i] = (f32x4){0.f, 0.f, 0.f, 0.f};
  float l_i[4] = {0.f, 0.f, 0.f, 0.f};

  ushort_t* sPw = sP[w];
  int bb = 0;

  for (int kt = 0; kt < ntiles; ++kt) {
    if (kt + 1 < ntiles) STAGE_KV(kt + 1, bb ^ 1);

    f32x4 cs[4];
#pragma unroll
    for (int nblk = 0; nblk < 4; ++nblk) {
      cs[nblk] = (f32x4){0.f, 0.f, 0.f, 0.f};
#pragma unroll
      for (int s = 0; s < 2; ++s) {
        bf16x8 kb = *(const bf16x8*)&sK[bb][s * 2048 + (nblk * 16 + col) * 32 + quad * 8];
        cs[nblk] = __builtin_amdgcn_mfma_f32_16x16x32_bf16(qa[s], kb, cs[nblk], 0, 0, 0);
      }
    }
    if (kt * 64 + 64 > Nk) {
#pragma unroll
      for (int nblk = 0; nblk < 4; ++nblk) {
        bool valid = (kt * 64 + nblk * 16 + col) < Nk;
#pragma unroll
        for (int r = 0; r < 4; ++r)
          cs[nblk][r] = valid ? cs[nblk][r] : -1e30f;
      }
    }
#pragma unroll
    for (int r = 0; r < 4; ++r) {
      int row = quad * 4 + r;
#pragma unroll
      for (int nblk = 0; nblk < 4; ++nblk) {
        float p = exp2f(fmaf(cs[nblk][r], scale, -M0));
        l_i[r] += p;
        int kin = (nblk & 1) * 16 + col;
        sPw[(nblk >> 1) * 512 + row * 32 + (kin ^ (quad << 3))] = f2b(p);
      }
    }
#pragma unroll
    for (int s = 0; s < 2; ++s) {
      bf16x8 pa = *(const bf16x8*)&sPw[s * 512 + col * 32 + ((quad ^ ((col >> 2) & 3)) << 3)];
#pragma unroll
      for (int nblk = 0; nblk < 4; ++nblk) {
        bf16x8 vb = *(const bf16x8*)&sV[bb][s * 2048 + (nblk * 16 + col) * 32 + quad * 8];
        oacc[nblk] = __builtin_amdgcn_mfma_f32_16x16x32_bf16(pa, vb, oacc[nblk], 0, 0, 0);
      }
    }
    if (kt + 1 < ntiles) __syncthreads();
    bb ^= 1;
  }
#undef STAGE_KV

#pragma unroll
  for (int r = 0; r < 4; ++r) {
    float ps = l_i[r];
#pragma unroll
    for (int o = 1; o < 16; o <<= 1) ps += __shfl_xor(ps, o);
    int qglob = b * N_DIM + q0 + w * 16 + quad * 4 + r;
    float inv = 1.f / ps;
#pragma unroll
    for (int nblk = 0; nblk < 4; ++nblk)
      O[(size_t)qglob * C_DIM + h * 64 + nblk * 16 + col] = f2b(oacc[nblk][r] * inv);
  }
}

// ---------------------------------------------------------------------------
extern "C" void kernel_launch(void* const* d_in, const int* in_sizes, int n_in,
                              void* d_out, int out_size, void* d_ws, size_t ws_size,
                              hipStream_t stream) {
  const float* x        = (const float*)d_in[0];
  const float* enc      = (const float*)d_in[1];
  const float* ln1_g    = (const float*)d_in[2];
  const float* ln1_b    = (const float*)d_in[3];
  const float* ln2_g    = (const float*)d_in[4];
  const float* ln2_b    = (const float*)d_in[5];
  const float* sa_wq    = (const float*)d_in[6];
  const float* sa_wk    = (const float*)d_in[7];
  const float* sa_wv    = (const float*)d_in[8];
  const float* sa_wo    = (const float*)d_in[9];
  const float* sa_wo_b  = (const float*)d_in[10];
  const float* ff_ln_g  = (const float*)d_in[11];
  const float* ff_ln_b  = (const float*)d_in[12];
  const float* ff_w1    = (const float*)d_in[13];
  const float* ff_w2    = (const float*)d_in[14];
  const float* a_attn   = (const float*)d_in[15];
  const float* a_dense  = (const float*)d_in[16];
  const float* ca_wq    = (const float*)d_in[17];
  const float* ca_wk    = (const float*)d_in[18];
  const float* ca_wv    = (const float*)d_in[19];
  const float* ca_wo    = (const float*)d_in[20];
  const float* ca_wo_b  = (const float*)d_in[21];

  char* ws = (char*)d_ws;
  float*    x1     = (float*)(ws + WX1);
  float*    x2     = (float*)(ws + WX2);
  ushort_t* qkv_b  = (ushort_t*)(ws + WQKV);
  ushort_t* q2b    = (ushort_t*)(ws + WQKV);
  ushort_t* kv2b   = (ushort_t*)(ws + WQKV + 3145728u);
  ushort_t* comb_b = (ushort_t*)(ws + WBB1);
  ushort_t* attn_b = (ushort_t*)(ws + WATTN);
  ushort_t* g_b    = (ushort_t*)(ws + WG);
  ushort_t* hh     = (ushort_t*)(ws + WS1);
  ushort_t* x2b    = (ushort_t*)(ws + WS1);
  ushort_t* text_b = (ushort_t*)(ws + WTEXT);
  ushort_t* attn2b = (ushort_t*)(ws + WATT2);
  ushort_t* wqkv_t = (ushort_t*)(ws + WWQKV);
  ushort_t* wo_t   = (ushort_t*)(ws + WWO);
  ushort_t* w1_t   = (ushort_t*)(ws + WW1);
  ushort_t* w2_t   = (ushort_t*)(ws + WW2);
  ushort_t* cawq_t = (ushort_t*)(ws + WCAWQ);
  ushort_t* cakv_t = (ushort_t*)(ws + WCAKV);
  ushort_t* cawo_t = (ushort_t*)(ws + WCAWO);
  ushort_t* vt1    = (ushort_t*)(ws + WVT1);
  ushort_t* vt2    = (ushort_t*)(ws + WVT2);
  float* part = (float*)(ws + WPART);
  float* out = (float*)d_out;

  const int Mc = B_DIM * NC_DIM;   // 2080
  const int Mx = B_DIM * N_DIM;    // 2048
  const int Mt = B_DIM * TEXT_LEN; // 154

  // ---- launch 1: weight transposes + LN/concat + text gather ----
  WtDesc wd;
  const float* srcs[10] = {sa_wq, sa_wk, sa_wv, sa_wo, ca_wq, ca_wk, ca_wv, ca_wo, ff_w1, ff_w2};
  ushort_t* dsts[10] = {wqkv_t, wqkv_t + 589824, wqkv_t + 2 * 589824, wo_t,
                        cawq_t, cakv_t, cakv_t + 589824, cawo_t, w1_t, w2_t};
  int Ks[10] = {768, 768, 768, 768, 768, 768, 768, 768, 768, 3072};
  int Ns[10] = {768, 768, 768, 768, 768, 768, 768, 768, 6144, 768};
  int total = 0;
  for (int j = 0; j < 10; ++j) {
    wd.src[j] = srcs[j]; wd.dst[j] = dsts[j];
    wd.K[j] = Ks[j]; wd.N[j] = Ns[j];
    wd.tilesX[j] = Ns[j] / 64;
    wd.ileave[j] = (j == 8) ? 1 : 0;
    wd.start[j] = total;
    total += (Ns[j] / 64) * (Ks[j] / 64);
  }
  wd.start[10] = total;   // 2880

  prep_kernel<<<total + Mc + Mt, 256, 0, stream>>>(
      wd, x, enc, ln1_g, ln1_b, comb_b, text_b);
  // ---- launch 2: qkv GEMM (y<33) + kv GEMM (y>=33, x<24) ----
  gemm64<<<dim3(36, 36, 1), 256, 0, stream>>>(
      comb_b, wqkv_t, nullptr, qkv_b, nullptr, Mc, 2304, 768, 768,
      nullptr, nullptr, nullptr,
      text_b, cakv_t, kv2b, Mt, 1536, 33);
  // ---- launch 3: V transposes (self x<17, cross x>=17) ----
  vtrans_kernel<<<dim3(19, 12, B_DIM), 256, 0, stream>>>(
      qkv_b + 1536, vt1, NC_DIM, 2304, NC_DIM, 1088,
      kv2b + 768, vt2, TEXT_LEN, 1536, TEXT_LEN, 128, 17);
  // ---- self-attn: single pass, in-kernel normalize (no merge) ----
  attn_mfma<<<dim3(N_DIM / 64, 12, B_DIM), 256, 0, stream>>>(
      qkv_b + 0, qkv_b + 768, vt1, attn_b,
      NC_DIM, NC_DIM, NC_DIM, 1088, 2304, 2304);
  // ---- wo: gemm64 z=1, fused bias+res+alpha, fp32 x1 out (no slabs) ----
  gemm64<<<dim3(12, 32, 1), 256, 0, stream>>>(
      attn_b, wo_t, x1, nullptr, nullptr, Mx, 768, 768, 768,
      sa_wo_b, x, a_attn,
      nullptr, nullptr, nullptr, 0, 0, 0);
  // ---- double layernorm from x1 -> hh ----
  woepi_ln_kernel<<<Mx, 256, 0, stream>>>(
      nullptr, 0, nullptr, x1, a_attn, x1, ln2_g, ln2_b, ff_ln_g, ff_ln_b, hh);
  // ---- ff1 + fused GEGLU (128-tile, pair-in-lane w1) -> g_b [2048][3072] ----
  gemm_bf16<<<dim3(48, 16), 256, 0, stream>>>(
      hh, w1_t, nullptr, g_b, Mx, 6144, 768);
  // ---- ff2: gemm64 split-K z=2 (768 blocks x 24 iters) -> splitk_epi ----
  gemm64<<<dim3(12, 32, 2), 256, 0, stream>>>(
      g_b, w2_t, nullptr, nullptr, part, Mx, 768, 3072, 1536,
      nullptr, nullptr, nullptr,
      nullptr, nullptr, nullptr, 0, 0, 0);
  splitk_epi<<<MNX / 1024, 256, 0, stream>>>(
      part, 2, x2, x2b, MNX, 768, nullptr, x1, a_dense);
  // ---- q2: gemm64 z=1, direct bf16 out ----
  gemm64<<<dim3(12, 32, 1), 256, 0, stream>>>(
      x2b, cawq_t, nullptr, q2b, nullptr, Mx, 768, 768, 768,
      nullptr, nullptr, nullptr,
      nullptr, nullptr, nullptr, 0, 0, 0);
  // ---- cross-attn: in-kernel normalize ----
  attn_mfma<<<dim3(N_DIM / 64, 12, B_DIM), 256, 0, stream>>>(
      q2b, kv2b + 0, vt2, attn2b,
      N_DIM, TEXT_LEN, TEXT_LEN, 128, 768, 1536);
  // ---- final: gemm64 z=1, fused bias+residual, fp32 out ----
  gemm64<<<dim3(12, 32, 1), 256, 0, stream>>>(
      attn2b, cawo_t, out, nullptr, nullptr, Mx, 768, 768, 768,
      ca_wo_b, x2, nullptr,
      nullptr, nullptr, nullptr, 0, 0, 0);
}

// Round 8
// 299.340 us; speedup vs baseline: 1.0250x; 1.0075x over previous
//
#include <hip/hip_runtime.h>
#include <hip/hip_bf16.h>
#include <math.h>

// ---------------------------------------------------------------------------
// FaceAttnProcessor forward. R17 (= R16 + kv2b relocation BUGFIX):
// - BUG (introduced R12): kv2b lived at WQKV+3.1MB, inside qkv_b
//   [2080][2304] (ends WQKV+9.58MB). The R12 merge of the kv GEMM into the
//   qkv launch made kv2b's write clobber qkv_b rows ~682-785 (batch-0 V/Q/K)
//   before self-attn read them -> absmax crept 0.0156->0.039 (R12-R15,
//   passing) and 0.127 (R16, failing) as block schedules shifted.
// - FIX: kv2b -> WBB1+12.58MB (after ff2's two split-K slabs; comb_b dead
//   after launch 2, part slabs never reach this offset, read at cross-attn).
// - qkv stays on the 128-tile GEMM (R16's change; indexing re-audited).
// B=2, N=1024, C=768, H=12, INNER=3072.
// ---------------------------------------------------------------------------

#define C_DIM 768
#define B_DIM 2
#define N_DIM 1024
#define NC_DIM 1040
#define L_DIM 93
#define TEXT_LEN 77
#define INNER 3072
#define MNX 1572864   // 2048*768

typedef unsigned short ushort_t;
typedef __bf16 bf16x8 __attribute__((ext_vector_type(8)));
typedef float f32x4 __attribute__((ext_vector_type(4)));

__device__ __forceinline__ ushort_t f2b(float f) {
  __hip_bfloat16 h = __float2bfloat16(f);
  return *(ushort_t*)&h;
}
__device__ __forceinline__ float b2f(ushort_t u) {
  __hip_bfloat16 h = *(__hip_bfloat16*)&u;
  return __bfloat162float(h);
}

__device__ __forceinline__ void g2lds16(const void* g, void* l) {
  __builtin_amdgcn_global_load_lds(
      (const __attribute__((address_space(1))) unsigned int*)g,
      (__attribute__((address_space(3))) unsigned int*)l, 16, 0, 0);
}

// ---------------- workspace map (byte offsets) ----------------------------
#define WX1    0u           // fp32 x1 (2048*768)
#define WX2    6291456u     // fp32 x2
#define WQKV   12582912u    // u16 qkv_b [2080][2304]; later q2b [2048][768]
#define WBB1   22167552u    // comb_b / split-K partial slabs (2x 6.29MB)
#define WKV2   34750464u    // u16 kv2b [154][1536] (after part slabs; live L2->L10)
#define WG     47333376u    // attn_b (phase A) / g_b (phase C)
#define WS1    59916288u    // u16 hh / x2b [2048][768]
#define WTEXT  63062016u    // u16 text_b [154][768]
#define WATT2  63298560u    // u16 attn2b [2048][768]
#define WWQKV  66444288u    // u16 wqkv_t [2304][768]
#define WWO    69983232u    // u16 wo_t   [768][768]
#define WW1    71162880u    // u16 w1_t   [6144][768] (pair-in-lane a/gate rows)
#define WW2    80600064u    // u16 w2_t   [768][3072]
#define WCAWQ  85318656u    // u16 cawq_t [768][768]
#define WCAKV  86498304u    // u16 cakv_t [1536][768]
#define WCAWO  88857600u    // u16 cawo_t [768][768]
#define WVT1   90037248u    // u16 Vt self  [2][12][64][1088]
#define WVT2   93379584u    // u16 Vt cross [2][12][64][128]
#define WATTN  (WG + 524288u)       // u16 attn_b (dead before g_b written)
#define WPART  WBB1                 // fp32 split-K partials (2 slabs = 12.58MB)
// end: 93,772,800 B

// ---------------- block reduction (256 threads = 4 waves) -----------------
__device__ __forceinline__ float block_sum(float v, float* sh) {
#pragma unroll
  for (int o = 32; o > 0; o >>= 1) v += __shfl_down(v, o);
  int lane = threadIdx.x & 63, w = threadIdx.x >> 6;
  if (lane == 0) sh[w] = v;
  __syncthreads();
  float r = sh[0] + sh[1] + sh[2] + sh[3];
  __syncthreads();
  return r;
}

// ---------------- prep: weight transposes + LN/concat + text gather -------
struct WtDesc {
  const float* src[10];
  ushort_t*    dst[10];
  int K[10];
  int N[10];
  int tilesX[10];
  int ileave[10];
  int start[11];
};

__global__ __launch_bounds__(256)
void prep_kernel(WtDesc d,
                 const float* __restrict__ x, const float* __restrict__ enc,
                 const float* __restrict__ g, const float* __restrict__ b,
                 ushort_t* __restrict__ comb, ushort_t* __restrict__ text) {
  __shared__ float tile[64][65];
  int bid = blockIdx.x;
  int nwt = d.start[10];
  if (bid >= nwt) {
    // ---- LN(x)/LN(face) -> comb, or text gather ----
    int r = bid - nwt;
    if (r >= B_DIM * NC_DIM) {
      int i = r - B_DIM * NC_DIM;
      int bb = i / TEXT_LEN, j = i % TEXT_LEN;
      const float* src = enc + ((size_t)bb * L_DIM + j) * C_DIM;
      ushort_t* dst = text + (size_t)i * C_DIM;
#pragma unroll
      for (int l = 0; l < 3; ++l) {
        int c = threadIdx.x + l * 256;
        dst[c] = f2b(src[c]);
      }
      return;
    }
    float* sh = &tile[0][0];
    int bb = r / NC_DIM, i = r % NC_DIM;
    const float* src = (i < N_DIM)
        ? (x   + ((size_t)bb * N_DIM + i) * C_DIM)
        : (enc + ((size_t)bb * L_DIM + TEXT_LEN + (i - N_DIM)) * C_DIM);
    float v[3];
#pragma unroll
    for (int j = 0; j < 3; ++j) v[j] = src[threadIdx.x + j * 256];
    float mean = block_sum(v[0] + v[1] + v[2], sh) * (1.f / C_DIM);
    float sq = 0.f;
#pragma unroll
    for (int j = 0; j < 3; ++j) { float dd = v[j] - mean; sq += dd * dd; }
    float rstd = rsqrtf(block_sum(sq, sh) * (1.f / C_DIM) + 1e-5f);
    ushort_t* dst = comb + (size_t)r * C_DIM;
#pragma unroll
    for (int j = 0; j < 3; ++j) {
      int c = threadIdx.x + j * 256;
      dst[c] = f2b((v[j] - mean) * rstd * g[c] + b[c]);
    }
    return;
  }
  // ---- weight cast+transpose ----
  int j = 0;
  while (j < 9 && bid >= d.start[j + 1]) ++j;
  int ti = bid - d.start[j];
  int K = d.K[j], N = d.N[j];
  int n0 = (ti % d.tilesX[j]) * 64, k0 = (ti / d.tilesX[j]) * 64;
  const float* in = d.src[j];
  ushort_t* out = d.dst[j];
  int il = d.ileave[j];
  int t = threadIdx.x;
#pragma unroll
  for (int p = 0; p < 16; ++p) {
    int idx = t + p * 256;
    int r = idx >> 6, c = idx & 63;
    tile[r][c] = in[(size_t)(k0 + r) * N + n0 + c];
  }
  __syncthreads();
#pragma unroll
  for (int p = 0; p < 16; ++p) {
    int idx = t + p * 256;
    int r = idx >> 6, c = idx & 63;
    int nrow = n0 + r;
    int dstrow;
    if (il) {
      // pair-in-lane GEGLU layout: a-col c -> (c>>4)*32+(c&15); gate +16
      int cc = (nrow < INNER) ? nrow : (nrow - INNER);
      dstrow = ((cc >> 4) << 5) + (cc & 15) + ((nrow < INNER) ? 0 : 16);
    } else {
      dstrow = nrow;
    }
    out[(size_t)dstrow * K + k0 + c] = f2b(tile[c][r]);
  }
}

// ---------------- bf16 MFMA GEMM, 128x128 tile -----------------------------
// Paths: Og!=null -> fused GEGLU (pair-in-lane a/gate rows); else bf16 Ob.
// Optional second problem: blocks with blockIdx.y >= ybreak compute
// {A2,Bt2}->Ob2 (bf16 out) -- used to merge kv into the qkv launch.
__global__ __launch_bounds__(256)
void gemm_bf16(const ushort_t* __restrict__ A, const ushort_t* __restrict__ Bt,
               ushort_t* __restrict__ Ob, ushort_t* __restrict__ Og,
               int M, int N, int K,
               const ushort_t* __restrict__ A2, const ushort_t* __restrict__ Bt2,
               ushort_t* __restrict__ Ob2, int M2, int N2, int ybreak) {
  __shared__ ushort_t sA[2][128 * 32];
  __shared__ ushort_t sB[2][128 * 32];
  int by = blockIdx.y;
  if (A2 && by >= ybreak) {
    if ((int)blockIdx.x * 128 >= N2) return;
    A = A2; Bt = Bt2; Ob = Ob2; Og = nullptr; M = M2; N = N2;
    by -= ybreak;
  }
  int t = threadIdx.x;
  int w = t >> 6, ln = t & 63;
  int m0 = by * 128, n0 = blockIdx.x * 128;
  int wm = (w >> 1) * 64, wn = (w & 1) * 64;
  int lr = ln & 15, lq = ln >> 4;
  int seg_r = ln >> 2, seg_c = (ln & 3) * 8;

  f32x4 acc[4][4];
#pragma unroll
  for (int mi = 0; mi < 4; ++mi)
#pragma unroll
    for (int ni = 0; ni < 4; ++ni) acc[mi][ni] = (f32x4){0.f, 0.f, 0.f, 0.f};

#define STAGE(k0_, buf_)                                                     \
  do {                                                                       \
    _Pragma("unroll") for (int l = 0; l < 2; ++l) {                          \
      int s = w * 2 + l;                                                     \
      int arow = m0 + s * 16 + seg_r;                                        \
      arow = arow < M ? arow : M - 1;                                        \
      g2lds16(A + (size_t)arow * K + (k0_) + seg_c, &sA[buf_][s * 512]);     \
      int nrow = n0 + s * 16 + seg_r;                                        \
      g2lds16(Bt + (size_t)nrow * K + (k0_) + seg_c, &sB[buf_][s * 512]);    \
    }                                                                        \
  } while (0)

  STAGE(0, 0);
  __syncthreads();
  int cur = 0;
  for (int k0 = 0; k0 < K; k0 += 32) {
    if (k0 + 32 < K) STAGE(k0 + 32, cur ^ 1);
    bf16x8 af[4], bfr[4];
#pragma unroll
    for (int mi = 0; mi < 4; ++mi)
      af[mi] = *(const bf16x8*)&sA[cur][(wm + mi * 16 + lr) * 32 + lq * 8];
#pragma unroll
    for (int ni = 0; ni < 4; ++ni)
      bfr[ni] = *(const bf16x8*)&sB[cur][(wn + ni * 16 + lr) * 32 + lq * 8];
#pragma unroll
    for (int mi = 0; mi < 4; ++mi)
#pragma unroll
      for (int ni = 0; ni < 4; ++ni)
        acc[mi][ni] = __builtin_amdgcn_mfma_f32_16x16x32_bf16(
            af[mi], bfr[ni], acc[mi][ni], 0, 0, 0);
    __syncthreads();
    cur ^= 1;
  }
#undef STAGE

  if (Og) {
    // pair-in-lane GEGLU: acc[mi][2p] = a, acc[mi][2p+1] = gate, same lane.
    // output col c = (n0+wn)/2 + p*16 + lr
    int cbase = ((n0 + wn) >> 1) + lr;
#pragma unroll
    for (int mi = 0; mi < 4; ++mi)
#pragma unroll
      for (int p = 0; p < 2; ++p) {
        int c = cbase + p * 16;
#pragma unroll
        for (int r = 0; r < 4; ++r) {
          float a = acc[mi][2 * p][r];
          float gate = acc[mi][2 * p + 1][r];
          float ge = 0.5f * gate * (1.f + erff(gate * 0.70710678118654752f));
          int row = m0 + wm + mi * 16 + lq * 4 + r;
          Og[(size_t)row * INNER + c] = f2b(a * ge);
        }
      }
  } else {
#pragma unroll
    for (int mi = 0; mi < 4; ++mi)
#pragma unroll
      for (int ni = 0; ni < 4; ++ni) {
        int col = n0 + wn + ni * 16 + lr;
#pragma unroll
        for (int r = 0; r < 4; ++r) {
          int row = m0 + wm + mi * 16 + lq * 4 + r;
          if (row < M) Ob[(size_t)row * N + col] = f2b(acc[mi][ni][r]);
        }
      }
  }
}

// ---------------- bf16 MFMA GEMM, 64x64 tile, BK=64, optional split-K ------
// 4 waves, each 32x32 subtile (2x2 MFMA). grid.z = K/Ksplit splits;
// Part!=null: fp32 partial slabs; else fused bias/res/alpha epilogue.
__global__ __launch_bounds__(256)
void gemm64(const ushort_t* __restrict__ A, const ushort_t* __restrict__ Bt,
            float* __restrict__ Out, ushort_t* __restrict__ Ob,
            float* __restrict__ Part,
            int M, int N, int K, int Ksplit,
            const float* __restrict__ bias, const float* __restrict__ res,
            const float* __restrict__ alphaPtr) {
  __shared__ ushort_t sA[2][4096];   // [buf][s*2048 + row*32 + k]
  __shared__ ushort_t sB[2][4096];
  int by = blockIdx.y;
  int t = threadIdx.x;
  int w = t >> 6, ln = t & 63;
  int m0 = by * 64, n0 = blockIdx.x * 64;
  int wm = (w >> 1) * 32, wn = (w & 1) * 32;
  int lr = ln & 15, lq = ln >> 4;
  int srow = (w & 1) * 32 + (ln >> 2);        // staging row (+ i*16)
  int skoff = (w >> 1) * 32 + (ln & 3) * 8;   // staging k offset
  int kbeg = blockIdx.z * Ksplit;
  int kend = kbeg + Ksplit; if (kend > K) kend = K;

  f32x4 acc[2][2];
#pragma unroll
  for (int mi = 0; mi < 2; ++mi)
#pragma unroll
    for (int ni = 0; ni < 2; ++ni) acc[mi][ni] = (f32x4){0.f, 0.f, 0.f, 0.f};

#define STG64(k0_, buf_)                                                      \
  do {                                                                        \
    _Pragma("unroll") for (int i = 0; i < 2; ++i) {                           \
      int ar = m0 + srow + i * 16; ar = ar < M ? ar : M - 1;                  \
      g2lds16(A + (size_t)ar * K + (k0_) + skoff,                             \
              (char*)sA + (buf_) * 8192 + w * 2048 + i * 1024);               \
      int nr = n0 + srow + i * 16;                                            \
      g2lds16(Bt + (size_t)nr * K + (k0_) + skoff,                            \
              (char*)sB + (buf_) * 8192 + w * 2048 + i * 1024);               \
    }                                                                         \
  } while (0)

  STG64(kbeg, 0);
  __syncthreads();
  int cur = 0;
  for (int k0 = kbeg; k0 < kend; k0 += 64) {
    if (k0 + 64 < kend) STG64(k0 + 64, cur ^ 1);
#pragma unroll
    for (int s = 0; s < 2; ++s) {
      bf16x8 a0 = *(const bf16x8*)&sA[cur][s * 2048 + (wm + lr) * 32 + lq * 8];
      bf16x8 a1 = *(const bf16x8*)&sA[cur][s * 2048 + (wm + 16 + lr) * 32 + lq * 8];
      bf16x8 b0 = *(const bf16x8*)&sB[cur][s * 2048 + (wn + lr) * 32 + lq * 8];
      bf16x8 b1 = *(const bf16x8*)&sB[cur][s * 2048 + (wn + 16 + lr) * 32 + lq * 8];
      acc[0][0] = __builtin_amdgcn_mfma_f32_16x16x32_bf16(a0, b0, acc[0][0], 0, 0, 0);
      acc[0][1] = __builtin_amdgcn_mfma_f32_16x16x32_bf16(a0, b1, acc[0][1], 0, 0, 0);
      acc[1][0] = __builtin_amdgcn_mfma_f32_16x16x32_bf16(a1, b0, acc[1][0], 0, 0, 0);
      acc[1][1] = __builtin_amdgcn_mfma_f32_16x16x32_bf16(a1, b1, acc[1][1], 0, 0, 0);
    }
    __syncthreads();
    cur ^= 1;
  }
#undef STG64

  if (Part) {
    float* P = Part + (size_t)blockIdx.z * M * N;
#pragma unroll
    for (int mi = 0; mi < 2; ++mi)
#pragma unroll
      for (int ni = 0; ni < 2; ++ni) {
        int col = n0 + wn + ni * 16 + lr;
#pragma unroll
        for (int r = 0; r < 4; ++r) {
          int row = m0 + wm + mi * 16 + lq * 4 + r;
          if (row < M) P[(size_t)row * N + col] = acc[mi][ni][r];
        }
      }
  } else {
    float f = alphaPtr ? tanhf(alphaPtr[0]) : 1.0f;
#pragma unroll
    for (int mi = 0; mi < 2; ++mi)
#pragma unroll
      for (int ni = 0; ni < 2; ++ni) {
        int col = n0 + wn + ni * 16 + lr;
        float bv = bias ? bias[col] : 0.f;
#pragma unroll
        for (int r = 0; r < 4; ++r) {
          int row = m0 + wm + mi * 16 + lq * 4 + r;
          if (row < M) {
            float val = acc[mi][ni][r] + bv;
            if (res) val = res[(size_t)row * N + col] + f * val;
            if (Out) Out[(size_t)row * N + col] = val;
            if (Ob)  Ob[(size_t)row * N + col] = f2b(val);
          }
        }
      }
  }
}

// ---------------- split-K reduce epilogue ----------------------------------
__global__ __launch_bounds__(256)
void splitk_epi(const float* __restrict__ Part, int nz, float* __restrict__ Out,
                ushort_t* __restrict__ Ob, int MN, int N,
                const float* __restrict__ bias, const float* __restrict__ res,
                const float* __restrict__ alphaPtr) {
  int idx = (blockIdx.x * 256 + threadIdx.x) * 4;
  if (idx >= MN) return;
  float f = alphaPtr ? tanhf(alphaPtr[0]) : 1.0f;
  float v[4] = {0.f, 0.f, 0.f, 0.f};
  for (int z = 0; z < nz; ++z) {
    float4 a = *(const float4*)&Part[(size_t)z * MN + idx];
    v[0] += a.x; v[1] += a.y; v[2] += a.z; v[3] += a.w;
  }
  if (bias) {
    int col = idx % N;
    float4 bb = *(const float4*)&bias[col];
    v[0] += bb.x; v[1] += bb.y; v[2] += bb.z; v[3] += bb.w;
  }
  if (res) {
    float4 rr = *(const float4*)&res[idx];
    v[0] = rr.x + f * v[0]; v[1] = rr.y + f * v[1];
    v[2] = rr.z + f * v[2]; v[3] = rr.w + f * v[3];
  }
  if (Out) *(float4*)&Out[idx] = make_float4(v[0], v[1], v[2], v[3]);
  if (Ob) {
    ushort4 o;
    o.x = f2b(v[0]); o.y = f2b(v[1]); o.z = f2b(v[2]); o.w = f2b(v[3]);
    *(ushort4*)&Ob[idx] = o;
  }
}

// ---------------- wo-epilogue (optional) + double layernorm ---------------
// nz>0: xv = xres + tanh(alpha)*(sum(Part)+bias), write x1. nz==0: xv = xres
// (already final; bias/Part unused). Then double LN -> hh.
__global__ __launch_bounds__(256)
void woepi_ln_kernel(const float* __restrict__ Part, int nz,
                     const float* __restrict__ bias, const float* __restrict__ xres,
                     const float* __restrict__ alphaPtr, float* __restrict__ x1,
                     const float* __restrict__ g1, const float* __restrict__ b1,
                     const float* __restrict__ g2, const float* __restrict__ b2,
                     ushort_t* __restrict__ hh) {
  __shared__ float sh[4];
  int row = blockIdx.x;
  float f = tanhf(alphaPtr[0]);
  float v[3];
#pragma unroll
  for (int j = 0; j < 3; ++j) {
    int c = threadIdx.x + j * 256;
    float xv;
    if (nz > 0) {
      float s = 0.f;
      for (int z = 0; z < nz; ++z) s += Part[(size_t)z * MNX + (size_t)row * C_DIM + c];
      s += bias[c];
      xv = xres[(size_t)row * C_DIM + c] + f * s;
      x1[(size_t)row * C_DIM + c] = xv;
    } else {
      xv = xres[(size_t)row * C_DIM + c];
    }
    v[j] = xv;
  }
  float mean = block_sum(v[0] + v[1] + v[2], sh) * (1.f / C_DIM);
  float sq = 0.f;
#pragma unroll
  for (int j = 0; j < 3; ++j) { float d = v[j] - mean; sq += d * d; }
  float rstd = rsqrtf(block_sum(sq, sh) * (1.f / C_DIM) + 1e-5f);
  float y[3];
#pragma unroll
  for (int j = 0; j < 3; ++j) {
    int c = threadIdx.x + j * 256;
    y[j] = (v[j] - mean) * rstd * g1[c] + b1[c];
  }
  float mean2 = block_sum(y[0] + y[1] + y[2], sh) * (1.f / C_DIM);
  sq = 0.f;
#pragma unroll
  for (int j = 0; j < 3; ++j) { float d = y[j] - mean2; sq += d * d; }
  float rstd2 = rsqrtf(block_sum(sq, sh) * (1.f / C_DIM) + 1e-5f);
#pragma unroll
  for (int j = 0; j < 3; ++j) {
    int c = threadIdx.x + j * 256;
    hh[(size_t)row * C_DIM + c] = f2b((y[j] - mean2) * rstd2 * g2[c] + b2[c]);
  }
}

// ---------------- V transpose: strided bf16 [key][64] -> Vt [dv][Nkp] -----
// Handles self (blocks x < xbreak) and cross (x >= xbreak) in one launch.
__global__ __launch_bounds__(256)
void vtrans_kernel(const ushort_t* __restrict__ V, ushort_t* __restrict__ Vt,
                   int rows_per_b, int stride, int Nk, int Nkp,
                   const ushort_t* __restrict__ V2, ushort_t* __restrict__ Vt2,
                   int rows2, int stride2, int Nk2, int Nkp2, int xbreak) {
  __shared__ ushort_t tile[64][68];
  int bx = blockIdx.x;
  if (bx >= xbreak) {
    bx -= xbreak;
    V = V2; Vt = Vt2; rows_per_b = rows2; stride = stride2; Nk = Nk2; Nkp = Nkp2;
  }
  int k0 = bx * 64;
  int h = blockIdx.y, b = blockIdx.z;
  int t = threadIdx.x;
#pragma unroll
  for (int p = 0; p < 4; ++p) {
    int r = p * 16 + (t >> 4), c = (t & 15) * 4;
    int key = k0 + r;
    ushort4 u = make_ushort4(0, 0, 0, 0);
    if (key < Nk)
      u = *(const ushort4*)&V[((size_t)(b * rows_per_b + key)) * stride + h * 64 + c];
    *(ushort4*)&tile[r][c] = u;
  }
  __syncthreads();
  size_t base = ((size_t)(b * 12 + h)) * 64 * Nkp;
#pragma unroll
  for (int p = 0; p < 4; ++p) {
    int dv = p * 16 + (t >> 4), kc = (t & 15) * 4;
    ushort4 u;
    u.x = tile[kc + 0][dv]; u.y = tile[kc + 1][dv];
    u.z = tile[kc + 2][dv]; u.w = tile[kc + 3][dv];
    *(ushort4*)&Vt[base + (size_t)dv * Nkp + k0 + kc] = u;
  }
}

// ---------------- MFMA flash attention (static-max, in-kernel normalize) ---
__global__ __launch_bounds__(256)
void attn_mfma(const ushort_t* __restrict__ Q, const ushort_t* __restrict__ K,
               const ushort_t* __restrict__ Vt, ushort_t* __restrict__ O,
               int q_rows_per_b, int kv_rows_per_b, int Nk, int Nkp,
               int qstride, int kstride) {
  __shared__ ushort_t sQ[4096];
  __shared__ ushort_t sK[2][4096];
  __shared__ ushort_t sV[2][4096];
  __shared__ ushort_t sP[4][1024];
  const float scale = 0.18033688011112042f;   // 1/8 * log2(e)
  const float M0 = 16.0f;
  int t = threadIdx.x;
  int w = t >> 6, ln = t & 63;
  int col = ln & 15, quad = ln >> 4;
  int b = blockIdx.z;
  int h = blockIdx.y, q0 = blockIdx.x * 64;
  size_t vt_base = ((size_t)(b * 12 + h)) * 64 * Nkp;
  int ntiles = Nkp >> 6;

#define STAGE_KV(kt_, bb_)                                                    \
  do {                                                                        \
    _Pragma("unroll") for (int s = 0; s < 2; ++s) {                           \
      int key = (kt_) * 64 + w * 16 + (ln >> 2);                              \
      g2lds16(K + (size_t)(b * kv_rows_per_b + key) * kstride                 \
                + h * 64 + s * 32 + (ln & 3) * 8,                             \
              (char*)sK[bb_] + s * 4096 + w * 1024);                          \
      int dv = w * 16 + (ln >> 2);                                            \
      g2lds16(Vt + vt_base + (size_t)dv * Nkp                                 \
                + (kt_) * 64 + s * 32 + (ln & 3) * 8,                         \
              (char*)sV[bb_] + s * 4096 + w * 1024);                          \
    }                                                                         \
  } while (0)

#pragma unroll
  for (int s = 0; s < 2; ++s) {
    int r = q0 + w * 16 + (ln >> 2);
    g2lds16(Q + (size_t)(b * q_rows_per_b + r) * qstride + h * 64 + s * 32 + (ln & 3) * 8,
            (char*)sQ + s * 4096 + w * 1024);
  }
  STAGE_KV(0, 0);
  __syncthreads();
  bf16x8 qa[2];
#pragma unroll
  for (int s = 0; s < 2; ++s)
    qa[s] = *(const bf16x8*)&sQ[s * 2048 + (w * 16 + col) * 32 + quad * 8];

  f32x4 oacc[4];
#pragma unroll
  for (int i = 0; i < 4; ++i) oacc[i] = (f32x4){0.f, 0.f, 0.f, 0.f};
  float l_i[4] = {0.f, 0.f, 0.f, 0.f};

  ushort_t* sPw = sP[w];
  int bb = 0;

  for (int kt = 0; kt < ntiles; ++kt) {
    if (kt + 1 < ntiles) STAGE_KV(kt + 1, bb ^ 1);

    f32x4 cs[4];
#pragma unroll
    for (int nblk = 0; nblk < 4; ++nblk) {
      cs[nblk] = (f32x4){0.f, 0.f, 0.f, 0.f};
#pragma unroll
      for (int s = 0; s < 2; ++s) {
        bf16x8 kb = *(const bf16x8*)&sK[bb][s * 2048 + (nblk * 16 + col) * 32 + quad * 8];
        cs[nblk] = __builtin_amdgcn_mfma_f32_16x16x32_bf16(qa[s], kb, cs[nblk], 0, 0, 0);
      }
    }
    if (kt * 64 + 64 > Nk) {
#pragma unroll
      for (int nblk = 0; nblk < 4; ++nblk) {
        bool valid = (kt * 64 + nblk * 16 + col) < Nk;
#pragma unroll
        for (int r = 0; r < 4; ++r)
          cs[nblk][r] = valid ? cs[nblk][r] : -1e30f;
      }
    }
#pragma unroll
    for (int r = 0; r < 4; ++r) {
      int row = quad * 4 + r;
#pragma unroll
      for (int nblk = 0; nblk < 4; ++nblk) {
        float p = exp2f(fmaf(cs[nblk][r], scale, -M0));
        l_i[r] += p;
        int kin = (nblk & 1) * 16 + col;
        sPw[(nblk >> 1) * 512 + row * 32 + (kin ^ (quad << 3))] = f2b(p);
      }
    }
#pragma unroll
    for (int s = 0; s < 2; ++s) {
      bf16x8 pa = *(const bf16x8*)&sPw[s * 512 + col * 32 + ((quad ^ ((col >> 2) & 3)) << 3)];
#pragma unroll
      for (int nblk = 0; nblk < 4; ++nblk) {
        bf16x8 vb = *(const bf16x8*)&sV[bb][s * 2048 + (nblk * 16 + col) * 32 + quad * 8];
        oacc[nblk] = __builtin_amdgcn_mfma_f32_16x16x32_bf16(pa, vb, oacc[nblk], 0, 0, 0);
      }
    }
    if (kt + 1 < ntiles) __syncthreads();
    bb ^= 1;
  }
#undef STAGE_KV

#pragma unroll
  for (int r = 0; r < 4; ++r) {
    float ps = l_i[r];
#pragma unroll
    for (int o = 1; o < 16; o <<= 1) ps += __shfl_xor(ps, o);
    int qglob = b * N_DIM + q0 + w * 16 + quad * 4 + r;
    float inv = 1.f / ps;
#pragma unroll
    for (int nblk = 0; nblk < 4; ++nblk)
      O[(size_t)qglob * C_DIM + h * 64 + nblk * 16 + col] = f2b(oacc[nblk][r] * inv);
  }
}

// ---------------------------------------------------------------------------
extern "C" void kernel_launch(void* const* d_in, const int* in_sizes, int n_in,
                              void* d_out, int out_size, void* d_ws, size_t ws_size,
                              hipStream_t stream) {
  const float* x        = (const float*)d_in[0];
  const float* enc      = (const float*)d_in[1];
  const float* ln1_g    = (const float*)d_in[2];
  const float* ln1_b    = (const float*)d_in[3];
  const float* ln2_g    = (const float*)d_in[4];
  const float* ln2_b    = (const float*)d_in[5];
  const float* sa_wq    = (const float*)d_in[6];
  const float* sa_wk    = (const float*)d_in[7];
  const float* sa_wv    = (const float*)d_in[8];
  const float* sa_wo    = (const float*)d_in[9];
  const float* sa_wo_b  = (const float*)d_in[10];
  const float* ff_ln_g  = (const float*)d_in[11];
  const float* ff_ln_b  = (const float*)d_in[12];
  const float* ff_w1    = (const float*)d_in[13];
  const float* ff_w2    = (const float*)d_in[14];
  const float* a_attn   = (const float*)d_in[15];
  const float* a_dense  = (const float*)d_in[16];
  const float* ca_wq    = (const float*)d_in[17];
  const float* ca_wk    = (const float*)d_in[18];
  const float* ca_wv    = (const float*)d_in[19];
  const float* ca_wo    = (const float*)d_in[20];
  const float* ca_wo_b  = (const float*)d_in[21];

  char* ws = (char*)d_ws;
  float*    x1     = (float*)(ws + WX1);
  float*    x2     = (float*)(ws + WX2);
  ushort_t* qkv_b  = (ushort_t*)(ws + WQKV);
  ushort_t* q2b    = (ushort_t*)(ws + WQKV);
  ushort_t* kv2b   = (ushort_t*)(ws + WKV2);
  ushort_t* comb_b = (ushort_t*)(ws + WBB1);
  ushort_t* attn_b = (ushort_t*)(ws + WATTN);
  ushort_t* g_b    = (ushort_t*)(ws + WG);
  ushort_t* hh     = (ushort_t*)(ws + WS1);
  ushort_t* x2b    = (ushort_t*)(ws + WS1);
  ushort_t* text_b = (ushort_t*)(ws + WTEXT);
  ushort_t* attn2b = (ushort_t*)(ws + WATT2);
  ushort_t* wqkv_t = (ushort_t*)(ws + WWQKV);
  ushort_t* wo_t   = (ushort_t*)(ws + WWO);
  ushort_t* w1_t   = (ushort_t*)(ws + WW1);
  ushort_t* w2_t   = (ushort_t*)(ws + WW2);
  ushort_t* cawq_t = (ushort_t*)(ws + WCAWQ);
  ushort_t* cakv_t = (ushort_t*)(ws + WCAKV);
  ushort_t* cawo_t = (ushort_t*)(ws + WCAWO);
  ushort_t* vt1    = (ushort_t*)(ws + WVT1);
  ushort_t* vt2    = (ushort_t*)(ws + WVT2);
  float* part = (float*)(ws + WPART);
  float* out = (float*)d_out;

  const int Mc = B_DIM * NC_DIM;   // 2080
  const int Mx = B_DIM * N_DIM;    // 2048
  const int Mt = B_DIM * TEXT_LEN; // 154

  // ---- launch 1: weight transposes + LN/concat + text gather ----
  WtDesc wd;
  const float* srcs[10] = {sa_wq, sa_wk, sa_wv, sa_wo, ca_wq, ca_wk, ca_wv, ca_wo, ff_w1, ff_w2};
  ushort_t* dsts[10] = {wqkv_t, wqkv_t + 589824, wqkv_t + 2 * 589824, wo_t,
                        cawq_t, cakv_t, cakv_t + 589824, cawo_t, w1_t, w2_t};
  int Ks[10] = {768, 768, 768, 768, 768, 768, 768, 768, 768, 3072};
  int Ns[10] = {768, 768, 768, 768, 768, 768, 768, 768, 6144, 768};
  int total = 0;
  for (int j = 0; j < 10; ++j) {
    wd.src[j] = srcs[j]; wd.dst[j] = dsts[j];
    wd.K[j] = Ks[j]; wd.N[j] = Ns[j];
    wd.tilesX[j] = Ns[j] / 64;
    wd.ileave[j] = (j == 8) ? 1 : 0;
    wd.start[j] = total;
    total += (Ns[j] / 64) * (Ks[j] / 64);
  }
  wd.start[10] = total;   // 2880

  prep_kernel<<<total + Mc + Mt, 256, 0, stream>>>(
      wd, x, enc, ln1_g, ln1_b, comb_b, text_b);
  // ---- launch 2: qkv GEMM on 128-tile (y<17) + kv GEMM (y>=17, x<12) ----
  gemm_bf16<<<dim3(18, 19), 256, 0, stream>>>(
      comb_b, wqkv_t, qkv_b, nullptr, Mc, 2304, 768,
      text_b, cakv_t, kv2b, Mt, 1536, 17);
  // ---- launch 3: V transposes (self x<17, cross x>=17) ----
  vtrans_kernel<<<dim3(19, 12, B_DIM), 256, 0, stream>>>(
      qkv_b + 1536, vt1, NC_DIM, 2304, NC_DIM, 1088,
      kv2b + 768, vt2, TEXT_LEN, 1536, TEXT_LEN, 128, 17);
  // ---- self-attn: single pass, in-kernel normalize (no merge) ----
  attn_mfma<<<dim3(N_DIM / 64, 12, B_DIM), 256, 0, stream>>>(
      qkv_b + 0, qkv_b + 768, vt1, attn_b,
      NC_DIM, NC_DIM, NC_DIM, 1088, 2304, 2304);
  // ---- wo: gemm64 z=1, fused bias+res+alpha, fp32 x1 out (no slabs) ----
  gemm64<<<dim3(12, 32, 1), 256, 0, stream>>>(
      attn_b, wo_t, x1, nullptr, nullptr, Mx, 768, 768, 768,
      sa_wo_b, x, a_attn);
  // ---- double layernorm from x1 -> hh ----
  woepi_ln_kernel<<<Mx, 256, 0, stream>>>(
      nullptr, 0, nullptr, x1, a_attn, x1, ln2_g, ln2_b, ff_ln_g, ff_ln_b, hh);
  // ---- ff1 + fused GEGLU (128-tile, pair-in-lane w1) -> g_b [2048][3072] ----
  gemm_bf16<<<dim3(48, 16), 256, 0, stream>>>(
      hh, w1_t, nullptr, g_b, Mx, 6144, 768,
      nullptr, nullptr, nullptr, 0, 0, 0);
  // ---- ff2: gemm64 split-K z=2 (768 blocks x 24 iters) -> splitk_epi ----
  gemm64<<<dim3(12, 32, 2), 256, 0, stream>>>(
      g_b, w2_t, nullptr, nullptr, part, Mx, 768, 3072, 1536,
      nullptr, nullptr, nullptr);
  splitk_epi<<<MNX / 1024, 256, 0, stream>>>(
      part, 2, x2, x2b, MNX, 768, nullptr, x1, a_dense);
  // ---- q2: gemm64 z=1, direct bf16 out ----
  gemm64<<<dim3(12, 32, 1), 256, 0, stream>>>(
      x2b, cawq_t, nullptr, q2b, nullptr, Mx, 768, 768, 768,
      nullptr, nullptr, nullptr);
  // ---- cross-attn: in-kernel normalize ----
  attn_mfma<<<dim3(N_DIM / 64, 12, B_DIM), 256, 0, stream>>>(
      q2b, kv2b + 0, vt2, attn2b,
      N_DIM, TEXT_LEN, TEXT_LEN, 128, 768, 1536);
  // ---- final: gemm64 z=1, fused bias+residual, fp32 out ----
  gemm64<<<dim3(12, 32, 1), 256, 0, stream>>>(
      attn2b, cawo_t, out, nullptr, nullptr, Mx, 768, 768, 768,
      ca_wo_b, x2, nullptr);
}